// Round 2
// baseline (487.181 us; speedup 1.0000x reference)
//
#include <hip/hip_runtime.h>
#include <hip/hip_bf16.h>
#include <math.h>

#define HD   2048
#define DD   128
#define TT   4096
#define BB   4
#define MT   (BB*TT)     // 16384 tokens
#define LSEG 64
#define SSEG 64
#define NCOL 256
#define BKK  64
#define BMM  32
#define KSTEPS (HD/BKK)  // 32
#define SCALE_D 0.088388347648318447f  // 1/sqrt(128)

typedef _Float16 half8 __attribute__((ext_vector_type(8)));
typedef float    f32x4 __attribute__((ext_vector_type(4)));

__device__ __forceinline__ float sigmf(float x){ return 1.f/(1.f+__expf(-x)); }

// ---------------------------------------------------------------------------
// K_pre: pack B' = g (.) [sp_w | W_q] as fp16, n-major [256][2048]; per-col
// sums s_n = sum_h g*W, cb_n = sum_h b*W + bias; eta vector we2 = g*w_eta,
// scal = {s_eta, cb_eta, ns_acc=0, div_acc=0}
// ---------------------------------------------------------------------------
__global__ void k_pre(const float* __restrict__ ln_g, const float* __restrict__ ln_b,
                      const float* __restrict__ sp_w, const float* __restrict__ sp_b,
                      const float* __restrict__ W_qkv, const float* __restrict__ W_eta_w,
                      const float* __restrict__ W_eta_b,
                      _Float16* __restrict__ Bp, float* __restrict__ s_vec,
                      float* __restrict__ cb_vec, float* __restrict__ we2,
                      float* __restrict__ scal)
{
  __shared__ float red1[256], red2[256];
  int n = blockIdx.x, t = threadIdx.x;
  float sp = 0.f, cp = 0.f;
  if (n < NCOL) {
    for (int h = t; h < HD; h += 256) {
      float w = (n < DD) ? sp_w[(size_t)h*DD + n] : W_qkv[(size_t)h*384 + 256 + (n-DD)];
      float g = ln_g[h], b = ln_b[h];
      Bp[(size_t)n*HD + h] = (_Float16)(g*w);
      sp += g*w; cp += b*w;
    }
  } else {
    for (int h = t; h < HD; h += 256) {
      float w = W_eta_w[h];
      float g = ln_g[h], b = ln_b[h];
      we2[h] = g*w;
      sp += g*w; cp += b*w;
    }
  }
  red1[t] = sp; red2[t] = cp;
  __syncthreads();
  for (int o = 128; o > 0; o >>= 1) {
    if (t < o) { red1[t] += red1[t+o]; red2[t] += red2[t+o]; }
    __syncthreads();
  }
  if (t == 0) {
    if (n < NCOL) {
      s_vec[n]  = red1[0];
      cb_vec[n] = red2[0] + ((n < DD) ? sp_b[n] : 0.f);
    } else {
      scal[0] = red1[0];
      scal[1] = red2[0] + W_eta_b[0];
      scal[2] = 0.f; scal[3] = 0.f;
    }
  }
}

// ---------------------------------------------------------------------------
// K1: fused LN + GEMM.  C[16384 x 256] = H @ B' with LN applied as epilogue
// affine using side-reduced row stats. Outputs H_mem, Q_r (fp32), eta_tok.
// BM=32, BN=256, BK=64, fp16 MFMA 16x16x32, 4 waves (each: 2 row-tiles x 4
// col-tiles), register-prefetch pipeline.
// ---------------------------------------------------------------------------
__launch_bounds__(256, 2)
__global__ void k1_gemm(const float* __restrict__ H, const _Float16* __restrict__ Bp,
                        const float* __restrict__ s_vec, const float* __restrict__ cb_vec,
                        const float* __restrict__ we2, const float* __restrict__ scal,
                        float* __restrict__ H_mem, float* __restrict__ Q_r,
                        float* __restrict__ eta_tok)
{
  __shared__ __align__(16) _Float16 Asb[BMM*72];    // row stride 72 halves (144B)
  __shared__ __align__(16) _Float16 Bsb[NCOL*72];   // [n][k] , stride 72 halves
  __shared__ float we_s[HD];
  __shared__ float mu_s[BMM], rs_s[BMM];
  int tid = threadIdx.x;
  int m0 = blockIdx.x * BMM;
  for (int i = tid; i < HD; i += 256) we_s[i] = we2[i];
  int ar = tid >> 3, acq = tid & 7;               // A loader: fixed row per thread
  const float* aptr = H + (size_t)(m0 + ar)*HD + acq*8;
  int nb = tid >> 3, part = tid & 7;              // B loader
  const float4* bbase = (const float4*)Bp;        // 1 float4 = 8 halves
  float4 a0, a1, br[8];
  f32x4 acc[2][4];
#pragma unroll
  for (int i=0;i<2;i++)
#pragma unroll
    for (int j=0;j<4;j++) acc[i][j] = (f32x4){0.f,0.f,0.f,0.f};
  float s1=0.f, s2=0.f, se=0.f;

  // prefetch k-step 0
  a0 = *(const float4*)(aptr);
  a1 = *(const float4*)(aptr + 4);
#pragma unroll
  for (int p=0;p<8;p++) br[p] = bbase[(size_t)(p*32+nb)*256 + part];

  int lane = tid & 63, w = tid >> 6;
  int arow = lane & 15;   // frag m/n index
  int kq   = lane >> 4;   // 0..3

  for (int kt = 0; kt < KSTEPS; ++kt) {
    int k0 = kt * BKK;
    __syncthreads();
    // stage A (+side stats on fp32 values)
    {
      float v[8] = {a0.x,a0.y,a0.z,a0.w,a1.x,a1.y,a1.z,a1.w};
      half8 hv;
#pragma unroll
      for (int j=0;j<8;j++) hv[j] = (_Float16)v[j];
      *(half8*)&Asb[ar*72 + acq*8] = hv;
      const float* wp = &we_s[k0 + acq*8];
#pragma unroll
      for (int j=0;j<8;j++) { s1 += v[j]; s2 += v[j]*v[j]; se += v[j]*wp[j]; }
    }
    // stage B
#pragma unroll
    for (int p=0;p<8;p++) *(float4*)&Bsb[(p*32+nb)*72 + part*8] = br[p];
    __syncthreads();
    // prefetch next tile (overlaps MFMA below)
    if (kt+1 < KSTEPS) {
      int kn = k0 + BKK;
      a0 = *(const float4*)(aptr + kn);
      a1 = *(const float4*)(aptr + kn + 4);
#pragma unroll
      for (int p=0;p<8;p++) br[p] = bbase[(size_t)(p*32+nb)*256 + part + (kn>>3)];
    }
    // MFMA
#pragma unroll
    for (int ks=0; ks<2; ++ks) {
      half8 af0 = *(half8*)&Asb[arow*72 + ks*32 + kq*8];
      half8 af1 = *(half8*)&Asb[(arow+16)*72 + ks*32 + kq*8];
#pragma unroll
      for (int ct=0; ct<4; ++ct) {
        half8 bf = *(half8*)&Bsb[(w*64 + ct*16 + arow)*72 + ks*32 + kq*8];
        acc[0][ct] = __builtin_amdgcn_mfma_f32_16x16x32_f16(af0, bf, acc[0][ct], 0,0,0);
        acc[1][ct] = __builtin_amdgcn_mfma_f32_16x16x32_f16(af1, bf, acc[1][ct], 0,0,0);
      }
    }
  }
  // row stats: reduce across the 8 loader threads of each row (same wave)
#pragma unroll
  for (int o=1;o<8;o<<=1) {
    s1 += __shfl_xor(s1, o);
    s2 += __shfl_xor(s2, o);
    se += __shfl_xor(se, o);
  }
  if ((tid & 7) == 0) {
    float mu   = s1 * (1.f/HD);
    float var  = s2 * (1.f/HD) - mu*mu;
    float rstd = rsqrtf(var + 1e-5f);
    mu_s[ar] = mu; rs_s[ar] = rstd;
    eta_tok[m0 + ar] = rstd*(se - mu*scal[0]) + scal[1];
  }
  __syncthreads();
  // epilogue: affine LN correction + scatter to H_mem / Q_r
#pragma unroll
  for (int ct=0; ct<4; ++ct) {
    int n = w*64 + ct*16 + arow;
    float sn = s_vec[n], cbn = cb_vec[n];
#pragma unroll
    for (int rt=0; rt<2; ++rt) {
#pragma unroll
      for (int r=0; r<4; ++r) {
        int ml = rt*16 + kq*4 + r;
        float outv = rs_s[ml]*(acc[rt][ct][r] - mu_s[ml]*sn) + cbn;
        size_t m = (size_t)(m0 + ml);
        if (n < DD) H_mem[m*DD + n]      = outv;
        else        Q_r[m*DD + (n-DD)]   = outv;
      }
    }
  }
}

// ---------------------------------------------------------------------------
// K2a: per segment (b,s): summary softmax -> Z_seg; eta_seg; write-attn
// softmax A over K; store A_seg, Zeta = Z*eta_seg, eta_seg.
// ---------------------------------------------------------------------------
__global__ void k2a(const float* __restrict__ H_mem, const float* __restrict__ eta_tok,
                    const float* __restrict__ sum_q, const float* __restrict__ Mmat,
                    const float* __restrict__ temp,
                    float* __restrict__ Zeta, float* __restrict__ A_seg,
                    float* __restrict__ eta_seg)
{
  __shared__ float Hs[64][129];
  __shared__ float sq[128];
  __shared__ float warr[64];
  __shared__ float Zs[128];
  __shared__ float red[4];
  __shared__ float eta_sh;
  int tid = threadIdx.x;            // 128 threads
  int b = blockIdx.x >> 6, s = blockIdx.x & 63;
  const float* seg = H_mem + ((size_t)b*TT + s*LSEG)*DD;
  const float4* seg4 = (const float4*)seg;
  for (int i = tid; i < 64*32; i += 128) {
    float4 v = seg4[i];
    int row = i >> 5, c4 = (i & 31) << 2;
    Hs[row][c4]=v.x; Hs[row][c4+1]=v.y; Hs[row][c4+2]=v.z; Hs[row][c4+3]=v.w;
  }
  sq[tid] = sum_q[tid];
  __syncthreads();
  if (tid < 64) {                    // summary softmax over L=64 (wave 0)
    float sc = 0.f;
    for (int d = 0; d < DD; ++d) sc += sq[d]*Hs[tid][d];
    sc *= SCALE_D;
    float mx = sc;
    for (int o=32;o>0;o>>=1) mx = fmaxf(mx, __shfl_xor(mx, o));
    float e = __expf(sc - mx);
    float sm = e;
    for (int o=32;o>0;o>>=1) sm += __shfl_xor(sm, o);
    warr[tid] = e / sm;
  } else {                           // eta_seg (wave 1)
    int l = tid - 64;
    float ev = eta_tok[(size_t)b*TT + s*LSEG + l];
    for (int o=32;o>0;o>>=1) ev = fmaxf(ev, __shfl_xor(ev, o));
    if (l == 0) eta_sh = sigmf(ev);
  }
  __syncthreads();
  {                                  // Z[d]
    float z = 0.f;
    for (int l = 0; l < 64; ++l) z += warr[l]*Hs[l][tid];
    Zs[tid] = z;
  }
  __syncthreads();
  // write-attn scores over K=128
  float s_scale = SCALE_D * __expf(temp[0]);
  const float* mrow = Mmat + ((size_t)b*DD + tid)*DD;
  float sc2 = 0.f;
  for (int d = 0; d < DD; d += 4) {
    float4 mv = *(const float4*)(mrow + d);
    sc2 += mv.x*Zs[d] + mv.y*Zs[d+1] + mv.z*Zs[d+2] + mv.w*Zs[d+3];
  }
  sc2 *= s_scale;
  float mx = sc2;
  for (int o=32;o>0;o>>=1) mx = fmaxf(mx, __shfl_xor(mx, o));
  if ((tid&63)==0) red[tid>>6] = mx;
  __syncthreads();
  mx = fmaxf(red[0], red[1]);
  float e = __expf(sc2 - mx);
  float sm = e;
  for (int o=32;o>0;o>>=1) sm += __shfl_xor(sm, o);
  if ((tid&63)==0) red[2 + (tid>>6)] = sm;
  __syncthreads();
  sm = red[2] + red[3];
  size_t base = ((size_t)b*SSEG + s)*DD;
  A_seg[base + tid] = e / sm;
  Zeta[base + tid]  = Zs[tid] * eta_sh;
  if (tid == 0) eta_seg[(size_t)b*SSEG + s] = eta_sh;
}

// ---------------------------------------------------------------------------
// K2b: DeltaM (k-chunk of 32 per block), M_new, row rnorms, norm_sq atomic.
// grid 16 = 4 b x 4 kq ; 256 threads
// ---------------------------------------------------------------------------
__global__ void k2b(const float* __restrict__ A_seg, const float* __restrict__ Zeta,
                    const float* __restrict__ eta_seg, const float* __restrict__ Mmat,
                    const float* __restrict__ eta_ch,
                    float* __restrict__ M_new, float* __restrict__ rns_arr,
                    float* __restrict__ scal)
{
  __shared__ float As[64][33];
  __shared__ __align__(16) float Zs[64*128];
  __shared__ float rowp[32][8];
  __shared__ float eta_av;
  __shared__ float redb[4];
  int tid = threadIdx.x;
  int b = blockIdx.x >> 2, kq = blockIdx.x & 3;
  for (int i = tid; i < 64*32; i += 256) {
    int s = i >> 5, j = i & 31;
    As[s][j] = A_seg[((size_t)b*SSEG + s)*DD + kq*32 + j];
  }
  const float4* z4 = (const float4*)(Zeta + (size_t)b*SSEG*DD);
  float4* zs4 = (float4*)Zs;
  for (int i = tid; i < 64*32; i += 256) zs4[i] = z4[i];
  if (tid < 64) {
    float ev = eta_seg[(size_t)b*SSEG + tid];
    for (int o=32;o>0;o>>=1) ev += __shfl_xor(ev, o);
    if (tid == 0) eta_av = ev * (1.f/SSEG);
  }
  __syncthreads();
  int kl = tid & 31, dg = tid >> 5;
  int k = kq*32 + kl, d0 = dg*16;
  float dm[16];
#pragma unroll
  for (int j=0;j<16;j++) dm[j]=0.f;
  for (int s = 0; s < 64; ++s) {
    float a = As[s][kl];
    const float* zr = &Zs[s*128 + d0];
#pragma unroll
    for (int j=0;j<16;j++) dm[j] += a * zr[j];
  }
  float nsq = 0.f;
#pragma unroll
  for (int j=0;j<16;j++) nsq += dm[j]*dm[j];
  float eav = eta_av;
  float mn[16];
  float ss = 0.f;
#pragma unroll
  for (int j=0;j<16;j++) {
    int d = d0 + j;
    float gate = eav * sigmf(eta_ch[d]);
    float v = (1.f - gate)*Mmat[((size_t)b*DD + k)*DD + d] + dm[j]*(1.f/SSEG);
    mn[j] = v; ss += v*v;
  }
#pragma unroll
  for (int j=0;j<16;j+=4) {
    float4 v4; v4.x=mn[j]; v4.y=mn[j+1]; v4.z=mn[j+2]; v4.w=mn[j+3];
    *(float4*)&M_new[((size_t)b*DD + k)*DD + d0 + j] = v4;
  }
  rowp[kl][dg] = ss;
  for (int o=1;o<64;o<<=1) nsq += __shfl_xor(nsq, o);
  if ((tid&63)==0) redb[tid>>6] = nsq;
  __syncthreads();
  if (tid == 0) atomicAdd(&scal[2], redb[0]+redb[1]+redb[2]+redb[3]);
  if (tid < 32) {
    float t2 = 0.f;
#pragma unroll
    for (int g=0; g<8; ++g) t2 += rowp[tid][g];
    float nrm = sqrtf(t2);
    rns_arr[(size_t)b*DD + kq*32 + tid] = 1.f / fmaxf(nrm, 1e-12f);
  }
}

// ---------------------------------------------------------------------------
// K2d: diversity loss partials. grid 128 = 4 b x 32 kq (4 kk rows each).
// ---------------------------------------------------------------------------
__global__ void k2d(const float* __restrict__ M_new, const float* __restrict__ rns_arr,
                    float* __restrict__ scal)
{
  __shared__ float kr[4][128];
  __shared__ float redb[4];
  int tid = threadIdx.x;
  int b = blockIdx.x >> 5, kq = blockIdx.x & 31;
  for (int i = tid; i < 4*128; i += 256) {
    int ki = i >> 7, d = i & 127;
    kr[ki][d] = M_new[((size_t)b*DD + kq*4 + ki)*DD + d];
  }
  __syncthreads();
  int j = tid & 127, kh = tid >> 7;
  const float* mj = &M_new[((size_t)b*DD + j)*DD];
  float rj = rns_arr[(size_t)b*DD + j];
  float dv = 0.f;
#pragma unroll
  for (int ki2 = 0; ki2 < 2; ++ki2) {
    int kil = kh*2 + ki2;
    int kk = kq*4 + kil;
    float dot = 0.f;
    for (int d = 0; d < 128; d += 4) {
      float4 a = *(const float4*)(mj + d);
      dot += a.x*kr[kil][d] + a.y*kr[kil][d+1] + a.z*kr[kil][d+2] + a.w*kr[kil][d+3];
    }
    if (kk != j) {
      float sv = dot * rj * rns_arr[(size_t)b*DD + kk];
      dv += sv*sv;
    }
  }
  for (int o=1;o<64;o<<=1) dv += __shfl_xor(dv, o);
  if ((tid&63)==0) redb[tid>>6] = dv;
  __syncthreads();
  if (tid==0) atomicAdd(&scal[3], redb[0]+redb[1]+redb[2]+redb[3]);
}

// ---------------------------------------------------------------------------
// K3: read attention (fp32): r = 2*Q_r@M_new^T, softmax over K, C = A@M_new.
// grid 512 = 4 b x 128 token-groups(32). Also writes loss (block 0).
// Output C and loss are FLOAT32 (reference returns jnp.float32).
// ---------------------------------------------------------------------------
__global__ void k3(const float* __restrict__ Q_r, const float* __restrict__ M_new,
                   const float* __restrict__ scal,
                   float* __restrict__ out)
{
  __shared__ float Ms[128][129];
  __shared__ float Qs[2][128];
  __shared__ float Ar[2][128];
  __shared__ float red[8];
  int tid = threadIdx.x;   // 256
  int b = blockIdx.x >> 7;
  int t0 = (blockIdx.x & 127) * 32;
  if (blockIdx.x == 0 && tid == 0) {
    float loss = 0.01f*(scal[2]*(1.f/SSEG)) + 0.1f*(scal[3]*(1.f/(BB*DD*DD)));
    out[(size_t)MT*DD] = loss;
  }
  const float4* m4 = (const float4*)(M_new + (size_t)b*DD*DD);
  for (int i = tid; i < 128*32; i += 256) {
    float4 v = m4[i];
    int row = i >> 5, c = (i&31) << 2;
    Ms[row][c]=v.x; Ms[row][c+1]=v.y; Ms[row][c+2]=v.z; Ms[row][c+3]=v.w;
  }
  __syncthreads();
  int half = tid >> 7, idx = tid & 127;
  for (int tp = 0; tp < 16; ++tp) {
    int tok = t0 + tp*2 + half;
    size_t mrow = (size_t)b*TT + tok;
    Qs[half][idx] = Q_r[mrow*DD + idx];
    __syncthreads();
    float sc = 0.f;
    for (int d = 0; d < 128; ++d) sc += Qs[half][d]*Ms[idx][d];
    sc *= 2.f;
    float mx = sc;
    for (int o=32;o>0;o>>=1) mx = fmaxf(mx, __shfl_xor(mx, o));
    int wv = tid >> 6;
    if ((tid&63)==0) red[wv] = mx;
    __syncthreads();
    mx = fmaxf(red[half*2], red[half*2+1]);
    float e = __expf(sc - mx);
    float sm = e;
    for (int o=32;o>0;o>>=1) sm += __shfl_xor(sm, o);
    if ((tid&63)==0) red[4+wv] = sm;
    __syncthreads();
    sm = red[4+half*2] + red[4+half*2+1];
    Ar[half][idx] = e / sm;
    __syncthreads();
    float c = 0.f;
    for (int k = 0; k < 128; ++k) c += Ar[half][k]*Ms[k][idx];
    out[mrow*DD + idx] = c;
    __syncthreads();
  }
}

// ---------------------------------------------------------------------------
extern "C" void kernel_launch(void* const* d_in, const int* in_sizes, int n_in,
                              void* d_out, int out_size, void* d_ws, size_t ws_size,
                              hipStream_t stream)
{
  (void)in_sizes; (void)n_in; (void)out_size; (void)ws_size;
  const float* H       = (const float*)d_in[0];
  const float* Mmat    = (const float*)d_in[1];
  const float* ln_g    = (const float*)d_in[2];
  const float* ln_b    = (const float*)d_in[3];
  const float* W_eta_w = (const float*)d_in[4];
  const float* W_eta_b = (const float*)d_in[5];
  const float* sum_q   = (const float*)d_in[6];
  const float* sp_w    = (const float*)d_in[7];
  const float* sp_b    = (const float*)d_in[8];
  const float* eta_ch  = (const float*)d_in[9];
  const float* temp    = (const float*)d_in[10];
  const float* W_qkv   = (const float*)d_in[11];
  float* out           = (float*)d_out;

  char* wsb = (char*)d_ws;
  size_t off = 0;
  auto alloc = [&](size_t bytes) -> void* {
    void* p = wsb + off;
    off = (off + bytes + 255) & ~(size_t)255;
    return p;
  };
  _Float16* Bp   = (_Float16*)alloc((size_t)NCOL*HD*2);
  float* s_vec   = (float*)alloc(NCOL*4);
  float* cb_vec  = (float*)alloc(NCOL*4);
  float* we2     = (float*)alloc(HD*4);
  float* scal    = (float*)alloc(4*4);
  float* H_mem   = (float*)alloc((size_t)MT*DD*4);
  float* Q_r     = (float*)alloc((size_t)MT*DD*4);
  float* eta_tok = (float*)alloc((size_t)MT*4);
  float* Zeta    = (float*)alloc((size_t)BB*SSEG*DD*4);
  float* A_seg   = (float*)alloc((size_t)BB*SSEG*DD*4);
  float* eta_seg = (float*)alloc((size_t)BB*SSEG*4);
  float* M_new   = (float*)alloc((size_t)BB*DD*DD*4);
  float* rns_arr = (float*)alloc((size_t)BB*DD*4);

  hipLaunchKernelGGL(k_pre, dim3(NCOL+1), dim3(256), 0, stream,
                     ln_g, ln_b, sp_w, sp_b, W_qkv, W_eta_w, W_eta_b,
                     Bp, s_vec, cb_vec, we2, scal);
  hipLaunchKernelGGL(k1_gemm, dim3(MT/BMM), dim3(256), 0, stream,
                     H, Bp, s_vec, cb_vec, we2, scal, H_mem, Q_r, eta_tok);
  hipLaunchKernelGGL(k2a, dim3(BB*SSEG), dim3(128), 0, stream,
                     H_mem, eta_tok, sum_q, Mmat, temp, Zeta, A_seg, eta_seg);
  hipLaunchKernelGGL(k2b, dim3(16), dim3(256), 0, stream,
                     A_seg, Zeta, eta_seg, Mmat, eta_ch, M_new, rns_arr, scal);
  hipLaunchKernelGGL(k2d, dim3(128), dim3(256), 0, stream,
                     M_new, rns_arr, scal);
  hipLaunchKernelGGL(k3, dim3(512), dim3(256), 0, stream,
                     Q_r, M_new, scal, out);
}

// Round 3
// 368.478 us; speedup vs baseline: 1.3221x; 1.3221x over previous
//
#include <hip/hip_runtime.h>
#include <hip/hip_bf16.h>
#include <math.h>

#define HD   2048
#define DD   128
#define TT   4096
#define BB   4
#define MT   (BB*TT)     // 16384 tokens
#define LSEG 64
#define SSEG 64
#define NCOL 256
#define SCALE_D 0.088388347648318447f  // 1/sqrt(128)

typedef _Float16 half8 __attribute__((ext_vector_type(8)));
typedef _Float16 half4v __attribute__((ext_vector_type(4)));
typedef float    f32x4 __attribute__((ext_vector_type(4)));

__device__ __forceinline__ float sigmf(float x){ return 1.f/(1.f+__expf(-x)); }

__device__ __forceinline__ void glds16(const void* g, void* l) {
  __builtin_amdgcn_global_load_lds(
      (const __attribute__((address_space(1))) unsigned int*)g,
      (__attribute__((address_space(3))) unsigned int*)l, 16, 0, 0);
}

// ---------------------------------------------------------------------------
// K_pre: pack B' = g (.) [sp_w | W_q] as fp16, n-major [256][2048]; per-col
// sums s_n, cb_n; we2 = g*w_eta; scal = {s_eta, cb_eta, 0, 0}
// ---------------------------------------------------------------------------
__global__ void k_pre(const float* __restrict__ ln_g, const float* __restrict__ ln_b,
                      const float* __restrict__ sp_w, const float* __restrict__ sp_b,
                      const float* __restrict__ W_qkv, const float* __restrict__ W_eta_w,
                      const float* __restrict__ W_eta_b,
                      _Float16* __restrict__ Bp, float* __restrict__ s_vec,
                      float* __restrict__ cb_vec, float* __restrict__ we2,
                      float* __restrict__ scal)
{
  __shared__ float red1[256], red2[256];
  int n = blockIdx.x, t = threadIdx.x;
  float sp = 0.f, cp = 0.f;
  if (n < NCOL) {
    for (int h = t; h < HD; h += 256) {
      float w = (n < DD) ? sp_w[(size_t)h*DD + n] : W_qkv[(size_t)h*384 + 256 + (n-DD)];
      float g = ln_g[h], b = ln_b[h];
      Bp[(size_t)n*HD + h] = (_Float16)(g*w);
      sp += g*w; cp += b*w;
    }
  } else {
    for (int h = t; h < HD; h += 256) {
      float w = W_eta_w[h];
      float g = ln_g[h], b = ln_b[h];
      we2[h] = g*w;
      sp += g*w; cp += b*w;
    }
  }
  red1[t] = sp; red2[t] = cp;
  __syncthreads();
  for (int o = 128; o > 0; o >>= 1) {
    if (t < o) { red1[t] += red1[t+o]; red2[t] += red2[t+o]; }
    __syncthreads();
  }
  if (t == 0) {
    if (n < NCOL) {
      s_vec[n]  = red1[0];
      cb_vec[n] = red2[0] + ((n < DD) ? sp_b[n] : 0.f);
    } else {
      scal[0] = red1[0];
      scal[1] = red2[0] + W_eta_b[0];
      scal[2] = 0.f; scal[3] = 0.f;
    }
  }
}

// ---------------------------------------------------------------------------
// K0: stream H once: row stats (mu, rstd), eta_tok, and H16 = fp16(H).
// 512 blocks x 256 thr; each wave handles 8 rows (one at a time).
// ---------------------------------------------------------------------------
__launch_bounds__(256)
__global__ void k0_stats(const float* __restrict__ H, const float* __restrict__ we2,
                         const float* __restrict__ scal,
                         _Float16* __restrict__ H16, float* __restrict__ mu_arr,
                         float* __restrict__ rs_arr, float* __restrict__ eta_tok)
{
  int w = threadIdx.x >> 6, lane = threadIdx.x & 63;
  int m0 = blockIdx.x * 32;
  const float4* wr = (const float4*)we2;
  for (int i = 0; i < 8; ++i) {
    int row = m0 + i*4 + w;
    const float4* hr = (const float4*)(H + (size_t)row*HD);
    float s1 = 0.f, s2 = 0.f, se = 0.f;
#pragma unroll
    for (int j = 0; j < 8; ++j) {
      int pos = j*64 + lane;
      float4 v = hr[pos];
      float4 u = wr[pos];
      s1 += v.x + v.y + v.z + v.w;
      s2 += v.x*v.x + v.y*v.y + v.z*v.z + v.w*v.w;
      se += v.x*u.x + v.y*u.y + v.z*u.z + v.w*u.w;
      half4v h; h.x=(_Float16)v.x; h.y=(_Float16)v.y; h.z=(_Float16)v.z; h.w=(_Float16)v.w;
      *(half4v*)(H16 + (size_t)row*HD + pos*4) = h;
    }
#pragma unroll
    for (int o = 32; o > 0; o >>= 1) {
      s1 += __shfl_xor(s1, o);
      s2 += __shfl_xor(s2, o);
      se += __shfl_xor(se, o);
    }
    if (lane == 0) {
      float mu   = s1 * (1.f/HD);
      float var  = s2 * (1.f/HD) - mu*mu;
      float rstd = rsqrtf(var + 1e-5f);
      mu_arr[row] = mu; rs_arr[row] = rstd;
      eta_tok[row] = rstd*(se - mu*scal[0]) + scal[1];
    }
  }
}

// ---------------------------------------------------------------------------
// K1: fp16 GEMM C[16384 x 256] = H16 @ Bp^T, m97-style global_load_lds
// staging with XOR chunk swizzle; LN affine epilogue; coalesced writes via
// LDS. BM=64, BN=128, BK=64, 256 thr, 512 blocks (2/CU).
// ---------------------------------------------------------------------------
__launch_bounds__(256, 2)
__global__ void k1_gemm(const _Float16* __restrict__ A16, const _Float16* __restrict__ Bp,
                        const float* __restrict__ mu_arr, const float* __restrict__ rs_arr,
                        const float* __restrict__ s_vec, const float* __restrict__ cb_vec,
                        float* __restrict__ H_mem, float* __restrict__ Q_r)
{
  __shared__ __align__(16) _Float16 sA[64*64];    // 8 KB,  [row][k-chunk swizzled]
  __shared__ __align__(16) _Float16 sB[128*64];   // 16 KB, [n][k-chunk swizzled]
  __shared__ __align__(16) float    sC[64*132];   // 33 KB epilogue staging
  int tid = threadIdx.x;
  int mtile = blockIdx.x >> 1, ntile = blockIdx.x & 1;
  int m0 = mtile*64, n0 = ntile*128;
  int w = tid >> 6, lane = tid & 63, arow = lane & 15, kq = lane >> 4;
  int wm = w >> 1, wn = w & 1;
  f32x4 acc[2][4];
#pragma unroll
  for (int i = 0; i < 2; ++i)
#pragma unroll
    for (int j = 0; j < 4; ++j) acc[i][j] = (f32x4){0.f,0.f,0.f,0.f};

  const _Float16* Abase = A16 + (size_t)m0*HD;
  const _Float16* Bbase = Bp  + (size_t)n0*HD;
  int ia_row[2], ia_ch[2], ib_row[4], ib_ch[4];
#pragma unroll
  for (int i = 0; i < 2; ++i) {
    int idx = i*256 + tid;
    ia_row[i] = idx >> 3;
    ia_ch[i]  = (idx & 7) ^ (ia_row[i] & 7);   // swizzled source chunk
  }
#pragma unroll
  for (int i = 0; i < 4; ++i) {
    int idx = i*256 + tid;
    ib_row[i] = idx >> 3;
    ib_ch[i]  = (idx & 7) ^ (ib_row[i] & 7);
  }

  for (int kt = 0; kt < 32; ++kt) {
    int k0 = kt*64;
    __syncthreads();
#pragma unroll
    for (int i = 0; i < 2; ++i)
      glds16(Abase + (size_t)ia_row[i]*HD + k0 + ia_ch[i]*8, sA + (i*256 + tid)*8);
#pragma unroll
    for (int i = 0; i < 4; ++i)
      glds16(Bbase + (size_t)ib_row[i]*HD + k0 + ib_ch[i]*8, sB + (i*256 + tid)*8);
    __syncthreads();
#pragma unroll
    for (int ks = 0; ks < 2; ++ks) {
      half8 af[2], bf[4];
#pragma unroll
      for (int rt = 0; rt < 2; ++rt) {
        int r = wm*32 + rt*16 + arow;
        int ch = (ks*4 + kq) ^ (r & 7);
        af[rt] = *(half8*)&sA[r*64 + ch*8];
      }
#pragma unroll
      for (int ct = 0; ct < 4; ++ct) {
        int r = wn*64 + ct*16 + arow;
        int ch = (ks*4 + kq) ^ (r & 7);
        bf[ct] = *(half8*)&sB[r*64 + ch*8];
      }
#pragma unroll
      for (int rt = 0; rt < 2; ++rt)
#pragma unroll
        for (int ct = 0; ct < 4; ++ct)
          acc[rt][ct] = __builtin_amdgcn_mfma_f32_16x16x32_f16(af[rt], bf[ct], acc[rt][ct], 0,0,0);
    }
  }

  // epilogue: LN affine, stage to LDS, coalesced row writes
  float sn[4], cbn[4];
#pragma unroll
  for (int ct = 0; ct < 4; ++ct) {
    int n = wn*64 + ct*16 + arow;
    sn[ct] = s_vec[n0 + n]; cbn[ct] = cb_vec[n0 + n];
  }
#pragma unroll
  for (int rt = 0; rt < 2; ++rt) {
    int mb = wm*32 + rt*16 + kq*4;
#pragma unroll
    for (int r = 0; r < 4; ++r) {
      int m = mb + r;
      float mu = mu_arr[m0 + m], rs = rs_arr[m0 + m];
#pragma unroll
      for (int ct = 0; ct < 4; ++ct) {
        int n = wn*64 + ct*16 + arow;
        sC[m*132 + n] = rs*(acc[rt][ct][r] - mu*sn[ct]) + cbn[ct];
      }
    }
  }
  __syncthreads();
  float* dst = (ntile == 0) ? H_mem : Q_r;
#pragma unroll
  for (int j = 0; j < 8; ++j) {
    int idx = j*256 + tid;
    int row = idx >> 5, c4 = (idx & 31) * 4;
    float4 v = *(float4*)&sC[row*132 + c4];
    *(float4*)&dst[(size_t)(m0+row)*DD + c4] = v;
  }
}

// ---------------------------------------------------------------------------
// K2a: per segment (b,s): summary softmax -> Z_seg; eta_seg; write-attn
// softmax A over K; store A_seg, Zeta = Z*eta_seg, eta_seg.
// ---------------------------------------------------------------------------
__global__ void k2a(const float* __restrict__ H_mem, const float* __restrict__ eta_tok,
                    const float* __restrict__ sum_q, const float* __restrict__ Mmat,
                    const float* __restrict__ temp,
                    float* __restrict__ Zeta, float* __restrict__ A_seg,
                    float* __restrict__ eta_seg)
{
  __shared__ float Hs[64][129];
  __shared__ float sq[128];
  __shared__ float warr[64];
  __shared__ float Zs[128];
  __shared__ float red[4];
  __shared__ float eta_sh;
  int tid = threadIdx.x;            // 128 threads
  int b = blockIdx.x >> 6, s = blockIdx.x & 63;
  const float* seg = H_mem + ((size_t)b*TT + s*LSEG)*DD;
  const float4* seg4 = (const float4*)seg;
  for (int i = tid; i < 64*32; i += 128) {
    float4 v = seg4[i];
    int row = i >> 5, c4 = (i & 31) << 2;
    Hs[row][c4]=v.x; Hs[row][c4+1]=v.y; Hs[row][c4+2]=v.z; Hs[row][c4+3]=v.w;
  }
  sq[tid] = sum_q[tid];
  __syncthreads();
  if (tid < 64) {                    // summary softmax over L=64 (wave 0)
    float sc = 0.f;
    for (int d = 0; d < DD; ++d) sc += sq[d]*Hs[tid][d];
    sc *= SCALE_D;
    float mx = sc;
    for (int o=32;o>0;o>>=1) mx = fmaxf(mx, __shfl_xor(mx, o));
    float e = __expf(sc - mx);
    float sm = e;
    for (int o=32;o>0;o>>=1) sm += __shfl_xor(sm, o);
    warr[tid] = e / sm;
  } else {                           // eta_seg (wave 1)
    int l = tid - 64;
    float ev = eta_tok[(size_t)b*TT + s*LSEG + l];
    for (int o=32;o>0;o>>=1) ev = fmaxf(ev, __shfl_xor(ev, o));
    if (l == 0) eta_sh = sigmf(ev);
  }
  __syncthreads();
  {                                  // Z[d]
    float z = 0.f;
    for (int l = 0; l < 64; ++l) z += warr[l]*Hs[l][tid];
    Zs[tid] = z;
  }
  __syncthreads();
  // write-attn scores over K=128
  float s_scale = SCALE_D * __expf(temp[0]);
  const float* mrow = Mmat + ((size_t)b*DD + tid)*DD;
  float sc2 = 0.f;
  for (int d = 0; d < DD; d += 4) {
    float4 mv = *(const float4*)(mrow + d);
    sc2 += mv.x*Zs[d] + mv.y*Zs[d+1] + mv.z*Zs[d+2] + mv.w*Zs[d+3];
  }
  sc2 *= s_scale;
  float mx = sc2;
  for (int o=32;o>0;o>>=1) mx = fmaxf(mx, __shfl_xor(mx, o));
  if ((tid&63)==0) red[tid>>6] = mx;
  __syncthreads();
  mx = fmaxf(red[0], red[1]);
  float e = __expf(sc2 - mx);
  float sm = e;
  for (int o=32;o>0;o>>=1) sm += __shfl_xor(sm, o);
  if ((tid&63)==0) red[2 + (tid>>6)] = sm;
  __syncthreads();
  sm = red[2] + red[3];
  size_t base = ((size_t)b*SSEG + s)*DD;
  A_seg[base + tid] = e / sm;
  Zeta[base + tid]  = Zs[tid] * eta_sh;
  if (tid == 0) eta_seg[(size_t)b*SSEG + s] = eta_sh;
}

// ---------------------------------------------------------------------------
// K2b: DeltaM (k-chunk of 32 per block), M_new, row rnorms, norm_sq atomic.
// ---------------------------------------------------------------------------
__global__ void k2b(const float* __restrict__ A_seg, const float* __restrict__ Zeta,
                    const float* __restrict__ eta_seg, const float* __restrict__ Mmat,
                    const float* __restrict__ eta_ch,
                    float* __restrict__ M_new, float* __restrict__ rns_arr,
                    float* __restrict__ scal)
{
  __shared__ float As[64][33];
  __shared__ __align__(16) float Zs[64*128];
  __shared__ float rowp[32][8];
  __shared__ float eta_av;
  __shared__ float redb[4];
  int tid = threadIdx.x;
  int b = blockIdx.x >> 2, kq = blockIdx.x & 3;
  for (int i = tid; i < 64*32; i += 256) {
    int s = i >> 5, j = i & 31;
    As[s][j] = A_seg[((size_t)b*SSEG + s)*DD + kq*32 + j];
  }
  const float4* z4 = (const float4*)(Zeta + (size_t)b*SSEG*DD);
  float4* zs4 = (float4*)Zs;
  for (int i = tid; i < 64*32; i += 256) zs4[i] = z4[i];
  if (tid < 64) {
    float ev = eta_seg[(size_t)b*SSEG + tid];
    for (int o=32;o>0;o>>=1) ev += __shfl_xor(ev, o);
    if (tid == 0) eta_av = ev * (1.f/SSEG);
  }
  __syncthreads();
  int kl = tid & 31, dg = tid >> 5;
  int k = kq*32 + kl, d0 = dg*16;
  float dm[16];
#pragma unroll
  for (int j=0;j<16;j++) dm[j]=0.f;
  for (int s = 0; s < 64; ++s) {
    float a = As[s][kl];
    const float* zr = &Zs[s*128 + d0];
#pragma unroll
    for (int j=0;j<16;j++) dm[j] += a * zr[j];
  }
  float nsq = 0.f;
#pragma unroll
  for (int j=0;j<16;j++) nsq += dm[j]*dm[j];
  float eav = eta_av;
  float mn[16];
  float ss = 0.f;
#pragma unroll
  for (int j=0;j<16;j++) {
    int d = d0 + j;
    float gate = eav * sigmf(eta_ch[d]);
    float v = (1.f - gate)*Mmat[((size_t)b*DD + k)*DD + d] + dm[j]*(1.f/SSEG);
    mn[j] = v; ss += v*v;
  }
#pragma unroll
  for (int j=0;j<16;j+=4) {
    float4 v4; v4.x=mn[j]; v4.y=mn[j+1]; v4.z=mn[j+2]; v4.w=mn[j+3];
    *(float4*)&M_new[((size_t)b*DD + k)*DD + d0 + j] = v4;
  }
  rowp[kl][dg] = ss;
  for (int o=1;o<64;o<<=1) nsq += __shfl_xor(nsq, o);
  if ((tid&63)==0) redb[tid>>6] = nsq;
  __syncthreads();
  if (tid == 0) atomicAdd(&scal[2], redb[0]+redb[1]+redb[2]+redb[3]);
  if (tid < 32) {
    float t2 = 0.f;
#pragma unroll
    for (int g=0; g<8; ++g) t2 += rowp[tid][g];
    float nrm = sqrtf(t2);
    rns_arr[(size_t)b*DD + kq*32 + tid] = 1.f / fmaxf(nrm, 1e-12f);
  }
}

// ---------------------------------------------------------------------------
// K2d: diversity loss partials.
// ---------------------------------------------------------------------------
__global__ void k2d(const float* __restrict__ M_new, const float* __restrict__ rns_arr,
                    float* __restrict__ scal)
{
  __shared__ float kr[4][128];
  __shared__ float redb[4];
  int tid = threadIdx.x;
  int b = blockIdx.x >> 5, kq = blockIdx.x & 31;
  for (int i = tid; i < 4*128; i += 256) {
    int ki = i >> 7, d = i & 127;
    kr[ki][d] = M_new[((size_t)b*DD + kq*4 + ki)*DD + d];
  }
  __syncthreads();
  int j = tid & 127, kh = tid >> 7;
  const float* mj = &M_new[((size_t)b*DD + j)*DD];
  float rj = rns_arr[(size_t)b*DD + j];
  float dv = 0.f;
#pragma unroll
  for (int ki2 = 0; ki2 < 2; ++ki2) {
    int kil = kh*2 + ki2;
    int kk = kq*4 + kil;
    float dot = 0.f;
    for (int d = 0; d < 128; d += 4) {
      float4 a = *(const float4*)(mj + d);
      dot += a.x*kr[kil][d] + a.y*kr[kil][d+1] + a.z*kr[kil][d+2] + a.w*kr[kil][d+3];
    }
    if (kk != j) {
      float sv = dot * rj * rns_arr[(size_t)b*DD + kk];
      dv += sv*sv;
    }
  }
  for (int o=1;o<64;o<<=1) dv += __shfl_xor(dv, o);
  if ((tid&63)==0) redb[tid>>6] = dv;
  __syncthreads();
  if (tid==0) atomicAdd(&scal[3], redb[0]+redb[1]+redb[2]+redb[3]);
}

// ---------------------------------------------------------------------------
// K3: read attention (fp32). Output C and loss are FLOAT32.
// ---------------------------------------------------------------------------
__global__ void k3(const float* __restrict__ Q_r, const float* __restrict__ M_new,
                   const float* __restrict__ scal,
                   float* __restrict__ out)
{
  __shared__ float Ms[128][129];
  __shared__ float Qs[2][128];
  __shared__ float Ar[2][128];
  __shared__ float red[8];
  int tid = threadIdx.x;   // 256
  int b = blockIdx.x >> 7;
  int t0 = (blockIdx.x & 127) * 32;
  if (blockIdx.x == 0 && tid == 0) {
    float loss = 0.01f*(scal[2]*(1.f/SSEG)) + 0.1f*(scal[3]*(1.f/(BB*DD*DD)));
    out[(size_t)MT*DD] = loss;
  }
  const float4* m4 = (const float4*)(M_new + (size_t)b*DD*DD);
  for (int i = tid; i < 128*32; i += 256) {
    float4 v = m4[i];
    int row = i >> 5, c = (i&31) << 2;
    Ms[row][c]=v.x; Ms[row][c+1]=v.y; Ms[row][c+2]=v.z; Ms[row][c+3]=v.w;
  }
  __syncthreads();
  int half = tid >> 7, idx = tid & 127;
  for (int tp = 0; tp < 16; ++tp) {
    int tok = t0 + tp*2 + half;
    size_t mrow = (size_t)b*TT + tok;
    Qs[half][idx] = Q_r[mrow*DD + idx];
    __syncthreads();
    float sc = 0.f;
    for (int d = 0; d < 128; ++d) sc += Qs[half][d]*Ms[idx][d];
    sc *= 2.f;
    float mx = sc;
    for (int o=32;o>0;o>>=1) mx = fmaxf(mx, __shfl_xor(mx, o));
    int wv = tid >> 6;
    if ((tid&63)==0) red[wv] = mx;
    __syncthreads();
    mx = fmaxf(red[half*2], red[half*2+1]);
    float e = __expf(sc - mx);
    float sm = e;
    for (int o=32;o>0;o>>=1) sm += __shfl_xor(sm, o);
    if ((tid&63)==0) red[4+wv] = sm;
    __syncthreads();
    sm = red[4+half*2] + red[4+half*2+1];
    Ar[half][idx] = e / sm;
    __syncthreads();
    float c = 0.f;
    for (int k = 0; k < 128; ++k) c += Ar[half][k]*Ms[k][idx];
    out[mrow*DD + idx] = c;
    __syncthreads();
  }
}

// ---------------------------------------------------------------------------
extern "C" void kernel_launch(void* const* d_in, const int* in_sizes, int n_in,
                              void* d_out, int out_size, void* d_ws, size_t ws_size,
                              hipStream_t stream)
{
  (void)in_sizes; (void)n_in; (void)out_size; (void)ws_size;
  const float* H       = (const float*)d_in[0];
  const float* Mmat    = (const float*)d_in[1];
  const float* ln_g    = (const float*)d_in[2];
  const float* ln_b    = (const float*)d_in[3];
  const float* W_eta_w = (const float*)d_in[4];
  const float* W_eta_b = (const float*)d_in[5];
  const float* sum_q   = (const float*)d_in[6];
  const float* sp_w    = (const float*)d_in[7];
  const float* sp_b    = (const float*)d_in[8];
  const float* eta_ch  = (const float*)d_in[9];
  const float* temp    = (const float*)d_in[10];
  const float* W_qkv   = (const float*)d_in[11];
  float* out           = (float*)d_out;

  char* wsb = (char*)d_ws;
  size_t off = 0;
  auto alloc = [&](size_t bytes) -> void* {
    void* p = wsb + off;
    off = (off + bytes + 255) & ~(size_t)255;
    return p;
  };
  _Float16* Bp   = (_Float16*)alloc((size_t)NCOL*HD*2);
  float* s_vec   = (float*)alloc(NCOL*4);
  float* cb_vec  = (float*)alloc(NCOL*4);
  float* we2     = (float*)alloc(HD*4);
  float* scal    = (float*)alloc(4*4);
  float* H_mem   = (float*)alloc((size_t)MT*DD*4);
  float* Q_r     = (float*)alloc((size_t)MT*DD*4);
  float* eta_tok = (float*)alloc((size_t)MT*4);
  float* mu_arr  = (float*)alloc((size_t)MT*4);
  float* rs_arr  = (float*)alloc((size_t)MT*4);
  float* Zeta    = (float*)alloc((size_t)BB*SSEG*DD*4);
  float* A_seg   = (float*)alloc((size_t)BB*SSEG*DD*4);
  float* eta_seg = (float*)alloc((size_t)BB*SSEG*4);
  float* M_new   = (float*)alloc((size_t)BB*DD*DD*4);
  float* rns_arr = (float*)alloc((size_t)BB*DD*4);
  _Float16* H16  = (_Float16*)alloc((size_t)MT*HD*2);

  hipLaunchKernelGGL(k_pre, dim3(NCOL+1), dim3(256), 0, stream,
                     ln_g, ln_b, sp_w, sp_b, W_qkv, W_eta_w, W_eta_b,
                     Bp, s_vec, cb_vec, we2, scal);
  hipLaunchKernelGGL(k0_stats, dim3(MT/32), dim3(256), 0, stream,
                     H, we2, scal, H16, mu_arr, rs_arr, eta_tok);
  hipLaunchKernelGGL(k1_gemm, dim3((MT/64)*2), dim3(256), 0, stream,
                     H16, Bp, mu_arr, rs_arr, s_vec, cb_vec, H_mem, Q_r);
  hipLaunchKernelGGL(k2a, dim3(BB*SSEG), dim3(128), 0, stream,
                     H_mem, eta_tok, sum_q, Mmat, temp, Zeta, A_seg, eta_seg);
  hipLaunchKernelGGL(k2b, dim3(16), dim3(256), 0, stream,
                     A_seg, Zeta, eta_seg, Mmat, eta_ch, M_new, rns_arr, scal);
  hipLaunchKernelGGL(k2d, dim3(128), dim3(256), 0, stream,
                     M_new, rns_arr, scal);
  hipLaunchKernelGGL(k3, dim3(512), dim3(256), 0, stream,
                     Q_r, M_new, scal, out);
}

// Round 4
// 303.112 us; speedup vs baseline: 1.6073x; 1.2157x over previous
//
#include <hip/hip_runtime.h>
#include <hip/hip_bf16.h>
#include <math.h>

#define HD   2048
#define DD   128
#define TT   4096
#define BB   4
#define MT   (BB*TT)     // 16384 tokens
#define LSEG 64
#define SSEG 64
#define NCOL 256
#define SCALE_D 0.088388347648318447f  // 1/sqrt(128)

typedef _Float16 half8 __attribute__((ext_vector_type(8)));
typedef _Float16 half4v __attribute__((ext_vector_type(4)));
typedef float    f32x4 __attribute__((ext_vector_type(4)));

__device__ __forceinline__ float sigmf(float x){ return 1.f/(1.f+__expf(-x)); }

__device__ __forceinline__ void glds16(const void* g, void* l) {
  __builtin_amdgcn_global_load_lds(
      (const __attribute__((address_space(1))) unsigned int*)g,
      (__attribute__((address_space(3))) unsigned int*)l, 16, 0, 0);
}

// ---------------------------------------------------------------------------
// K_pre: pack B' = g (.) [sp_w | W_q] as fp16, n-major [256][2048]; per-col
// sums s_n, cb_n; we2 = g*w_eta; scal = {s_eta, cb_eta, 0, 0}
// ---------------------------------------------------------------------------
__global__ void k_pre(const float* __restrict__ ln_g, const float* __restrict__ ln_b,
                      const float* __restrict__ sp_w, const float* __restrict__ sp_b,
                      const float* __restrict__ W_qkv, const float* __restrict__ W_eta_w,
                      const float* __restrict__ W_eta_b,
                      _Float16* __restrict__ Bp, float* __restrict__ s_vec,
                      float* __restrict__ cb_vec, float* __restrict__ we2,
                      float* __restrict__ scal)
{
  __shared__ float red1[256], red2[256];
  int n = blockIdx.x, t = threadIdx.x;
  float sp = 0.f, cp = 0.f;
  if (n < NCOL) {
    for (int h = t; h < HD; h += 256) {
      float w = (n < DD) ? sp_w[(size_t)h*DD + n] : W_qkv[(size_t)h*384 + 256 + (n-DD)];
      float g = ln_g[h], b = ln_b[h];
      Bp[(size_t)n*HD + h] = (_Float16)(g*w);
      sp += g*w; cp += b*w;
    }
  } else {
    for (int h = t; h < HD; h += 256) {
      float w = W_eta_w[h];
      float g = ln_g[h], b = ln_b[h];
      we2[h] = g*w;
      sp += g*w; cp += b*w;
    }
  }
  red1[t] = sp; red2[t] = cp;
  __syncthreads();
  for (int o = 128; o > 0; o >>= 1) {
    if (t < o) { red1[t] += red1[t+o]; red2[t] += red2[t+o]; }
    __syncthreads();
  }
  if (t == 0) {
    if (n < NCOL) {
      s_vec[n]  = red1[0];
      cb_vec[n] = red2[0] + ((n < DD) ? sp_b[n] : 0.f);
    } else {
      scal[0] = red1[0];
      scal[1] = red2[0] + W_eta_b[0];
      scal[2] = 0.f; scal[3] = 0.f;
    }
  }
}

// ---------------------------------------------------------------------------
// K0: stream H once: row stats (mu, rstd), eta_tok, and H16 = fp16(H).
// ---------------------------------------------------------------------------
__launch_bounds__(256)
__global__ void k0_stats(const float* __restrict__ H, const float* __restrict__ we2,
                         const float* __restrict__ scal,
                         _Float16* __restrict__ H16, float* __restrict__ mu_arr,
                         float* __restrict__ rs_arr, float* __restrict__ eta_tok)
{
  int w = threadIdx.x >> 6, lane = threadIdx.x & 63;
  int m0 = blockIdx.x * 32;
  const float4* wr = (const float4*)we2;
  for (int i = 0; i < 8; ++i) {
    int row = m0 + i*4 + w;
    const float4* hr = (const float4*)(H + (size_t)row*HD);
    float s1 = 0.f, s2 = 0.f, se = 0.f;
#pragma unroll
    for (int j = 0; j < 8; ++j) {
      int pos = j*64 + lane;
      float4 v = hr[pos];
      float4 u = wr[pos];
      s1 += v.x + v.y + v.z + v.w;
      s2 += v.x*v.x + v.y*v.y + v.z*v.z + v.w*v.w;
      se += v.x*u.x + v.y*u.y + v.z*u.z + v.w*u.w;
      half4v h; h.x=(_Float16)v.x; h.y=(_Float16)v.y; h.z=(_Float16)v.z; h.w=(_Float16)v.w;
      *(half4v*)(H16 + (size_t)row*HD + pos*4) = h;
    }
#pragma unroll
    for (int o = 32; o > 0; o >>= 1) {
      s1 += __shfl_xor(s1, o);
      s2 += __shfl_xor(s2, o);
      se += __shfl_xor(se, o);
    }
    if (lane == 0) {
      float mu   = s1 * (1.f/HD);
      float var  = s2 * (1.f/HD) - mu*mu;
      float rstd = rsqrtf(var + 1e-5f);
      mu_arr[row] = mu; rs_arr[row] = rstd;
      eta_tok[row] = rstd*(se - mu*scal[0]) + scal[1];
    }
  }
}

// ---------------------------------------------------------------------------
// K1: fp16 GEMM C[16384 x 256] = H16 @ Bp^T, global_load_lds staging with
// XOR chunk swizzle; LN affine epilogue; coalesced writes via LDS.
// ---------------------------------------------------------------------------
__launch_bounds__(256, 2)
__global__ void k1_gemm(const _Float16* __restrict__ A16, const _Float16* __restrict__ Bp,
                        const float* __restrict__ mu_arr, const float* __restrict__ rs_arr,
                        const float* __restrict__ s_vec, const float* __restrict__ cb_vec,
                        float* __restrict__ H_mem, float* __restrict__ Q_r)
{
  __shared__ __align__(16) _Float16 sA[64*64];    // 8 KB
  __shared__ __align__(16) _Float16 sB[128*64];   // 16 KB
  __shared__ __align__(16) float    sC[64*132];   // 33 KB epilogue staging
  int tid = threadIdx.x;
  int mtile = blockIdx.x >> 1, ntile = blockIdx.x & 1;
  int m0 = mtile*64, n0 = ntile*128;
  int w = tid >> 6, lane = tid & 63, arow = lane & 15, kq = lane >> 4;
  int wm = w >> 1, wn = w & 1;
  f32x4 acc[2][4];
#pragma unroll
  for (int i = 0; i < 2; ++i)
#pragma unroll
    for (int j = 0; j < 4; ++j) acc[i][j] = (f32x4){0.f,0.f,0.f,0.f};

  const _Float16* Abase = A16 + (size_t)m0*HD;
  const _Float16* Bbase = Bp  + (size_t)n0*HD;
  int ia_row[2], ia_ch[2], ib_row[4], ib_ch[4];
#pragma unroll
  for (int i = 0; i < 2; ++i) {
    int idx = i*256 + tid;
    ia_row[i] = idx >> 3;
    ia_ch[i]  = (idx & 7) ^ (ia_row[i] & 7);
  }
#pragma unroll
  for (int i = 0; i < 4; ++i) {
    int idx = i*256 + tid;
    ib_row[i] = idx >> 3;
    ib_ch[i]  = (idx & 7) ^ (ib_row[i] & 7);
  }

  for (int kt = 0; kt < 32; ++kt) {
    int k0 = kt*64;
    __syncthreads();
#pragma unroll
    for (int i = 0; i < 2; ++i)
      glds16(Abase + (size_t)ia_row[i]*HD + k0 + ia_ch[i]*8, sA + (i*256 + tid)*8);
#pragma unroll
    for (int i = 0; i < 4; ++i)
      glds16(Bbase + (size_t)ib_row[i]*HD + k0 + ib_ch[i]*8, sB + (i*256 + tid)*8);
    __syncthreads();
#pragma unroll
    for (int ks = 0; ks < 2; ++ks) {
      half8 af[2], bf[4];
#pragma unroll
      for (int rt = 0; rt < 2; ++rt) {
        int r = wm*32 + rt*16 + arow;
        int ch = (ks*4 + kq) ^ (r & 7);
        af[rt] = *(half8*)&sA[r*64 + ch*8];
      }
#pragma unroll
      for (int ct = 0; ct < 4; ++ct) {
        int r = wn*64 + ct*16 + arow;
        int ch = (ks*4 + kq) ^ (r & 7);
        bf[ct] = *(half8*)&sB[r*64 + ch*8];
      }
#pragma unroll
      for (int rt = 0; rt < 2; ++rt)
#pragma unroll
        for (int ct = 0; ct < 4; ++ct)
          acc[rt][ct] = __builtin_amdgcn_mfma_f32_16x16x32_f16(af[rt], bf[ct], acc[rt][ct], 0,0,0);
    }
  }

  float sn[4], cbn[4];
#pragma unroll
  for (int ct = 0; ct < 4; ++ct) {
    int n = wn*64 + ct*16 + arow;
    sn[ct] = s_vec[n0 + n]; cbn[ct] = cb_vec[n0 + n];
  }
#pragma unroll
  for (int rt = 0; rt < 2; ++rt) {
    int mb = wm*32 + rt*16 + kq*4;
#pragma unroll
    for (int r = 0; r < 4; ++r) {
      int m = mb + r;
      float mu = mu_arr[m0 + m], rs = rs_arr[m0 + m];
#pragma unroll
      for (int ct = 0; ct < 4; ++ct) {
        int n = wn*64 + ct*16 + arow;
        sC[m*132 + n] = rs*(acc[rt][ct][r] - mu*sn[ct]) + cbn[ct];
      }
    }
  }
  __syncthreads();
  float* dst = (ntile == 0) ? H_mem : Q_r;
#pragma unroll
  for (int j = 0; j < 8; ++j) {
    int idx = j*256 + tid;
    int row = idx >> 5, c4 = (idx & 31) * 4;
    float4 v = *(float4*)&sC[row*132 + c4];
    *(float4*)&dst[(size_t)(m0+row)*DD + c4] = v;
  }
}

// ---------------------------------------------------------------------------
// K2a: per segment (b,s): summary softmax -> Z_seg; eta_seg; write-attn
// softmax A over K; store A_seg, Zeta = Z*eta_seg, eta_seg.
// ---------------------------------------------------------------------------
__global__ void k2a(const float* __restrict__ H_mem, const float* __restrict__ eta_tok,
                    const float* __restrict__ sum_q, const float* __restrict__ Mmat,
                    const float* __restrict__ temp,
                    float* __restrict__ Zeta, float* __restrict__ A_seg,
                    float* __restrict__ eta_seg)
{
  __shared__ float Hs[64][129];
  __shared__ float sq[128];
  __shared__ float warr[64];
  __shared__ float Zs[128];
  __shared__ float red[4];
  __shared__ float eta_sh;
  int tid = threadIdx.x;            // 128 threads
  int b = blockIdx.x >> 6, s = blockIdx.x & 63;
  const float* seg = H_mem + ((size_t)b*TT + s*LSEG)*DD;
  const float4* seg4 = (const float4*)seg;
  for (int i = tid; i < 64*32; i += 128) {
    float4 v = seg4[i];
    int row = i >> 5, c4 = (i & 31) << 2;
    Hs[row][c4]=v.x; Hs[row][c4+1]=v.y; Hs[row][c4+2]=v.z; Hs[row][c4+3]=v.w;
  }
  sq[tid] = sum_q[tid];
  __syncthreads();
  if (tid < 64) {
    float sc = 0.f;
    for (int d = 0; d < DD; ++d) sc += sq[d]*Hs[tid][d];
    sc *= SCALE_D;
    float mx = sc;
    for (int o=32;o>0;o>>=1) mx = fmaxf(mx, __shfl_xor(mx, o));
    float e = __expf(sc - mx);
    float sm = e;
    for (int o=32;o>0;o>>=1) sm += __shfl_xor(sm, o);
    warr[tid] = e / sm;
  } else {
    int l = tid - 64;
    float ev = eta_tok[(size_t)b*TT + s*LSEG + l];
    for (int o=32;o>0;o>>=1) ev = fmaxf(ev, __shfl_xor(ev, o));
    if (l == 0) eta_sh = sigmf(ev);
  }
  __syncthreads();
  {
    float z = 0.f;
    for (int l = 0; l < 64; ++l) z += warr[l]*Hs[l][tid];
    Zs[tid] = z;
  }
  __syncthreads();
  float s_scale = SCALE_D * __expf(temp[0]);
  const float* mrow = Mmat + ((size_t)b*DD + tid)*DD;
  float sc2 = 0.f;
  for (int d = 0; d < DD; d += 4) {
    float4 mv = *(const float4*)(mrow + d);
    sc2 += mv.x*Zs[d] + mv.y*Zs[d+1] + mv.z*Zs[d+2] + mv.w*Zs[d+3];
  }
  sc2 *= s_scale;
  float mx = sc2;
  for (int o=32;o>0;o>>=1) mx = fmaxf(mx, __shfl_xor(mx, o));
  if ((tid&63)==0) red[tid>>6] = mx;
  __syncthreads();
  mx = fmaxf(red[0], red[1]);
  float e = __expf(sc2 - mx);
  float sm = e;
  for (int o=32;o>0;o>>=1) sm += __shfl_xor(sm, o);
  if ((tid&63)==0) red[2 + (tid>>6)] = sm;
  __syncthreads();
  sm = red[2] + red[3];
  size_t base = ((size_t)b*SSEG + s)*DD;
  A_seg[base + tid] = e / sm;
  Zeta[base + tid]  = Zs[tid] * eta_sh;
  if (tid == 0) eta_seg[(size_t)b*SSEG + s] = eta_sh;
}

// ---------------------------------------------------------------------------
// K2b: DeltaM (k-chunk of 32 per block), M_new, row rnorms, norm_sq atomic.
// ---------------------------------------------------------------------------
__global__ void k2b(const float* __restrict__ A_seg, const float* __restrict__ Zeta,
                    const float* __restrict__ eta_seg, const float* __restrict__ Mmat,
                    const float* __restrict__ eta_ch,
                    float* __restrict__ M_new, float* __restrict__ rns_arr,
                    float* __restrict__ scal)
{
  __shared__ float As[64][33];
  __shared__ __align__(16) float Zs[64*128];
  __shared__ float rowp[32][8];
  __shared__ float eta_av;
  __shared__ float redb[4];
  int tid = threadIdx.x;
  int b = blockIdx.x >> 2, kq = blockIdx.x & 3;
  for (int i = tid; i < 64*32; i += 256) {
    int s = i >> 5, j = i & 31;
    As[s][j] = A_seg[((size_t)b*SSEG + s)*DD + kq*32 + j];
  }
  const float4* z4 = (const float4*)(Zeta + (size_t)b*SSEG*DD);
  float4* zs4 = (float4*)Zs;
  for (int i = tid; i < 64*32; i += 256) zs4[i] = z4[i];
  if (tid < 64) {
    float ev = eta_seg[(size_t)b*SSEG + tid];
    for (int o=32;o>0;o>>=1) ev += __shfl_xor(ev, o);
    if (tid == 0) eta_av = ev * (1.f/SSEG);
  }
  __syncthreads();
  int kl = tid & 31, dg = tid >> 5;
  int k = kq*32 + kl, d0 = dg*16;
  float dm[16];
#pragma unroll
  for (int j=0;j<16;j++) dm[j]=0.f;
  for (int s = 0; s < 64; ++s) {
    float a = As[s][kl];
    const float* zr = &Zs[s*128 + d0];
#pragma unroll
    for (int j=0;j<16;j++) dm[j] += a * zr[j];
  }
  float nsq = 0.f;
#pragma unroll
  for (int j=0;j<16;j++) nsq += dm[j]*dm[j];
  float eav = eta_av;
  float mn[16];
  float ss = 0.f;
#pragma unroll
  for (int j=0;j<16;j++) {
    int d = d0 + j;
    float gate = eav * sigmf(eta_ch[d]);
    float v = (1.f - gate)*Mmat[((size_t)b*DD + k)*DD + d] + dm[j]*(1.f/SSEG);
    mn[j] = v; ss += v*v;
  }
#pragma unroll
  for (int j=0;j<16;j+=4) {
    float4 v4; v4.x=mn[j]; v4.y=mn[j+1]; v4.z=mn[j+2]; v4.w=mn[j+3];
    *(float4*)&M_new[((size_t)b*DD + k)*DD + d0 + j] = v4;
  }
  rowp[kl][dg] = ss;
  for (int o=1;o<64;o<<=1) nsq += __shfl_xor(nsq, o);
  if ((tid&63)==0) redb[tid>>6] = nsq;
  __syncthreads();
  if (tid == 0) atomicAdd(&scal[2], redb[0]+redb[1]+redb[2]+redb[3]);
  if (tid < 32) {
    float t2 = 0.f;
#pragma unroll
    for (int g=0; g<8; ++g) t2 += rowp[tid][g];
    float nrm = sqrtf(t2);
    rns_arr[(size_t)b*DD + kq*32 + tid] = 1.f / fmaxf(nrm, 1e-12f);
  }
}

// ---------------------------------------------------------------------------
// K2d: diversity loss partials.
// ---------------------------------------------------------------------------
__global__ void k2d(const float* __restrict__ M_new, const float* __restrict__ rns_arr,
                    float* __restrict__ scal)
{
  __shared__ float kr[4][128];
  __shared__ float redb[4];
  int tid = threadIdx.x;
  int b = blockIdx.x >> 5, kq = blockIdx.x & 31;
  for (int i = tid; i < 4*128; i += 256) {
    int ki = i >> 7, d = i & 127;
    kr[ki][d] = M_new[((size_t)b*DD + kq*4 + ki)*DD + d];
  }
  __syncthreads();
  int j = tid & 127, kh = tid >> 7;
  const float* mj = &M_new[((size_t)b*DD + j)*DD];
  float rj = rns_arr[(size_t)b*DD + j];
  float dv = 0.f;
#pragma unroll
  for (int ki2 = 0; ki2 < 2; ++ki2) {
    int kil = kh*2 + ki2;
    int kk = kq*4 + kil;
    float dot = 0.f;
    for (int d = 0; d < 128; d += 4) {
      float4 a = *(const float4*)(mj + d);
      dot += a.x*kr[kil][d] + a.y*kr[kil][d+1] + a.z*kr[kil][d+2] + a.w*kr[kil][d+3];
    }
    if (kk != j) {
      float sv = dot * rj * rns_arr[(size_t)b*DD + kk];
      dv += sv*sv;
    }
  }
  for (int o=1;o<64;o<<=1) dv += __shfl_xor(dv, o);
  if ((tid&63)==0) redb[tid>>6] = dv;
  __syncthreads();
  if (tid==0) atomicAdd(&scal[3], redb[0]+redb[1]+redb[2]+redb[3]);
}

// ---------------------------------------------------------------------------
// K3: read attention via MFMA fp16 (fp32 softmax/accum).
// Per block: 64 tokens of one batch. M staged to LDS in both layouts fp16.
// Grid 256 = 4 b x 64 token-tiles, 256 thr (4 waves x 16 tokens).
// ---------------------------------------------------------------------------
__launch_bounds__(256, 1)
__global__ void k3(const float* __restrict__ Q_r, const float* __restrict__ M_new,
                   const float* __restrict__ scal, float* __restrict__ out)
{
  __shared__ __align__(16) _Float16 Mq[128*132];  // [key][d]   (QK B-frags)
  __shared__ __align__(16) _Float16 Mt[128*136];  // [d][key]   (PV B-frags)
  __shared__ __align__(16) _Float16 Ps[64*132];   // [token][key] (PV A-frags)
  int tid = threadIdx.x;
  int b = blockIdx.x >> 6, tile = blockIdx.x & 63;
  int t0 = tile*64;
  if (blockIdx.x == 0 && tid == 0) {
    float loss = 0.01f*(scal[2]*(1.f/SSEG)) + 0.1f*(scal[3]*(1.f/(BB*DD*DD)));
    out[(size_t)MT*DD] = loss;
  }
  // stage M (fp32 -> fp16) into natural + transposed layouts, 4x4 sub-blocks
  const float4* m4 = (const float4*)(M_new + (size_t)b*DD*DD);
#pragma unroll
  for (int it = 0; it < 4; ++it) {
    int sb = it*256 + tid;
    int rb = sb & 31, cb = sb >> 5;
    int r0 = rb*4, c0 = cb*4;
    float a[4][4];
#pragma unroll
    for (int j = 0; j < 4; ++j) {
      float4 v = m4[(size_t)(r0+j)*32 + cb];
      a[j][0]=v.x; a[j][1]=v.y; a[j][2]=v.z; a[j][3]=v.w;
    }
#pragma unroll
    for (int j = 0; j < 4; ++j) {
      half4v h; h.x=(_Float16)a[j][0]; h.y=(_Float16)a[j][1];
                h.z=(_Float16)a[j][2]; h.w=(_Float16)a[j][3];
      *(half4v*)&Mq[(r0+j)*132 + c0] = h;
    }
#pragma unroll
    for (int j2 = 0; j2 < 4; ++j2) {
      half4v h; h.x=(_Float16)a[0][j2]; h.y=(_Float16)a[1][j2];
                h.z=(_Float16)a[2][j2]; h.w=(_Float16)a[3][j2];
      *(half4v*)&Mt[(c0+j2)*136 + r0] = h;
    }
  }
  int w = tid >> 6, lane = tid & 63;
  int fcol = lane & 15, kq = lane >> 4;
  // Q A-frags: token = t0 + w*16 + fcol, k = ks*32 + kq*8 + j
  int tokA = t0 + w*16 + fcol;
  size_t qbase = ((size_t)b*TT + tokA)*DD;
  half8 af[4];
#pragma unroll
  for (int ks = 0; ks < 4; ++ks) {
    float4 q0 = *(const float4*)&Q_r[qbase + ks*32 + kq*8];
    float4 q1 = *(const float4*)&Q_r[qbase + ks*32 + kq*8 + 4];
    half8 h;
    h[0]=(_Float16)q0.x; h[1]=(_Float16)q0.y; h[2]=(_Float16)q0.z; h[3]=(_Float16)q0.w;
    h[4]=(_Float16)q1.x; h[5]=(_Float16)q1.y; h[6]=(_Float16)q1.z; h[7]=(_Float16)q1.w;
    af[ks] = h;
  }
  __syncthreads();
  // S = Q @ M^T  (n = key)
  f32x4 sacc[8];
#pragma unroll
  for (int nt = 0; nt < 8; ++nt) sacc[nt] = (f32x4){0.f,0.f,0.f,0.f};
#pragma unroll
  for (int nt = 0; nt < 8; ++nt)
#pragma unroll
    for (int ks = 0; ks < 4; ++ks) {
      half8 bf = *(half8*)&Mq[(nt*16 + fcol)*132 + ks*32 + kq*8];
      sacc[nt] = __builtin_amdgcn_mfma_f32_16x16x32_f16(af[ks], bf, sacc[nt], 0,0,0);
    }
  // softmax over 128 keys (x2 scale), fp32; rows live in (kq, reg)
#pragma unroll
  for (int nt = 0; nt < 8; ++nt)
#pragma unroll
    for (int r = 0; r < 4; ++r) sacc[nt][r] *= 2.f;
  float mx[4], sm[4];
#pragma unroll
  for (int r = 0; r < 4; ++r) {
    float m = sacc[0][r];
#pragma unroll
    for (int nt = 1; nt < 8; ++nt) m = fmaxf(m, sacc[nt][r]);
#pragma unroll
    for (int o = 1; o < 16; o <<= 1) m = fmaxf(m, __shfl_xor(m, o));
    mx[r] = m;
  }
#pragma unroll
  for (int r = 0; r < 4; ++r) sm[r] = 0.f;
#pragma unroll
  for (int nt = 0; nt < 8; ++nt)
#pragma unroll
    for (int r = 0; r < 4; ++r) {
      float e = __expf(sacc[nt][r] - mx[r]);
      sacc[nt][r] = e; sm[r] += e;
    }
#pragma unroll
  for (int r = 0; r < 4; ++r) {
    float s = sm[r];
#pragma unroll
    for (int o = 1; o < 16; o <<= 1) s += __shfl_xor(s, o);
    sm[r] = 1.f / s;
  }
  // write P to LDS [token][key] fp16 (C-layout -> A-layout round trip)
#pragma unroll
  for (int nt = 0; nt < 8; ++nt)
#pragma unroll
    for (int r = 0; r < 4; ++r) {
      int tk = w*16 + kq*4 + r;
      Ps[tk*132 + nt*16 + fcol] = (_Float16)(sacc[nt][r]*sm[r]);
    }
  __syncthreads();
  // C = P @ M  (n = d, k = key)
  half8 pf[4];
#pragma unroll
  for (int ks = 0; ks < 4; ++ks)
    pf[ks] = *(half8*)&Ps[(w*16 + fcol)*132 + ks*32 + kq*8];
  f32x4 cacc[8];
#pragma unroll
  for (int nt = 0; nt < 8; ++nt) cacc[nt] = (f32x4){0.f,0.f,0.f,0.f};
#pragma unroll
  for (int nt = 0; nt < 8; ++nt)
#pragma unroll
    for (int ks = 0; ks < 4; ++ks) {
      half8 bf = *(half8*)&Mt[(nt*16 + fcol)*136 + ks*32 + kq*8];
      cacc[nt] = __builtin_amdgcn_mfma_f32_16x16x32_f16(pf[ks], bf, cacc[nt], 0,0,0);
    }
#pragma unroll
  for (int nt = 0; nt < 8; ++nt)
#pragma unroll
    for (int r = 0; r < 4; ++r) {
      int tk = t0 + w*16 + kq*4 + r;
      out[((size_t)b*TT + tk)*DD + nt*16 + fcol] = cacc[nt][r];
    }
}

// ---------------------------------------------------------------------------
extern "C" void kernel_launch(void* const* d_in, const int* in_sizes, int n_in,
                              void* d_out, int out_size, void* d_ws, size_t ws_size,
                              hipStream_t stream)
{
  (void)in_sizes; (void)n_in; (void)out_size; (void)ws_size;
  const float* H       = (const float*)d_in[0];
  const float* Mmat    = (const float*)d_in[1];
  const float* ln_g    = (const float*)d_in[2];
  const float* ln_b    = (const float*)d_in[3];
  const float* W_eta_w = (const float*)d_in[4];
  const float* W_eta_b = (const float*)d_in[5];
  const float* sum_q   = (const float*)d_in[6];
  const float* sp_w    = (const float*)d_in[7];
  const float* sp_b    = (const float*)d_in[8];
  const float* eta_ch  = (const float*)d_in[9];
  const float* temp    = (const float*)d_in[10];
  const float* W_qkv   = (const float*)d_in[11];
  float* out           = (float*)d_out;

  char* wsb = (char*)d_ws;
  size_t off = 0;
  auto alloc = [&](size_t bytes) -> void* {
    void* p = wsb + off;
    off = (off + bytes + 255) & ~(size_t)255;
    return p;
  };
  _Float16* Bp   = (_Float16*)alloc((size_t)NCOL*HD*2);
  float* s_vec   = (float*)alloc(NCOL*4);
  float* cb_vec  = (float*)alloc(NCOL*4);
  float* we2     = (float*)alloc(HD*4);
  float* scal    = (float*)alloc(4*4);
  float* H_mem   = (float*)alloc((size_t)MT*DD*4);
  float* Q_r     = (float*)alloc((size_t)MT*DD*4);
  float* eta_tok = (float*)alloc((size_t)MT*4);
  float* mu_arr  = (float*)alloc((size_t)MT*4);
  float* rs_arr  = (float*)alloc((size_t)MT*4);
  float* Zeta    = (float*)alloc((size_t)BB*SSEG*DD*4);
  float* A_seg   = (float*)alloc((size_t)BB*SSEG*DD*4);
  float* eta_seg = (float*)alloc((size_t)BB*SSEG*4);
  float* M_new   = (float*)alloc((size_t)BB*DD*DD*4);
  float* rns_arr = (float*)alloc((size_t)BB*DD*4);
  _Float16* H16  = (_Float16*)alloc((size_t)MT*HD*2);

  hipLaunchKernelGGL(k_pre, dim3(NCOL+1), dim3(256), 0, stream,
                     ln_g, ln_b, sp_w, sp_b, W_qkv, W_eta_w, W_eta_b,
                     Bp, s_vec, cb_vec, we2, scal);
  hipLaunchKernelGGL(k0_stats, dim3(MT/32), dim3(256), 0, stream,
                     H, we2, scal, H16, mu_arr, rs_arr, eta_tok);
  hipLaunchKernelGGL(k1_gemm, dim3((MT/64)*2), dim3(256), 0, stream,
                     H16, Bp, mu_arr, rs_arr, s_vec, cb_vec, H_mem, Q_r);
  hipLaunchKernelGGL(k2a, dim3(BB*SSEG), dim3(128), 0, stream,
                     H_mem, eta_tok, sum_q, Mmat, temp, Zeta, A_seg, eta_seg);
  hipLaunchKernelGGL(k2b, dim3(16), dim3(256), 0, stream,
                     A_seg, Zeta, eta_seg, Mmat, eta_ch, M_new, rns_arr, scal);
  hipLaunchKernelGGL(k2d, dim3(128), dim3(256), 0, stream,
                     M_new, rns_arr, scal);
  hipLaunchKernelGGL(k3, dim3(256), dim3(256), 0, stream,
                     Q_r, M_new, scal, out);
}

// Round 5
// 290.440 us; speedup vs baseline: 1.6774x; 1.0436x over previous
//
#include <hip/hip_runtime.h>
#include <hip/hip_bf16.h>
#include <math.h>

#define HD   2048
#define DD   128
#define TT   4096
#define BB   4
#define MT   (BB*TT)     // 16384 tokens
#define LSEG 64
#define SSEG 64
#define NCOL 256
#define SCALE_D 0.088388347648318447f  // 1/sqrt(128)

typedef _Float16 half8 __attribute__((ext_vector_type(8)));
typedef _Float16 half4v __attribute__((ext_vector_type(4)));
typedef float    f32x4 __attribute__((ext_vector_type(4)));

__device__ __forceinline__ float sigmf(float x){ return 1.f/(1.f+__expf(-x)); }

__device__ __forceinline__ void glds16(const void* g, void* l) {
  __builtin_amdgcn_global_load_lds(
      (const __attribute__((address_space(1))) unsigned int*)g,
      (__attribute__((address_space(3))) unsigned int*)l, 16, 0, 0);
}

// ---------------------------------------------------------------------------
// K_pre: pack B' = g (.) [sp_w | W_q] as fp16, n-major [256][2048]; per-col
// sums s_n, cb_n; we2 = g*w_eta; scal = {s_eta, cb_eta, 0, 0}
// ---------------------------------------------------------------------------
__global__ void k_pre(const float* __restrict__ ln_g, const float* __restrict__ ln_b,
                      const float* __restrict__ sp_w, const float* __restrict__ sp_b,
                      const float* __restrict__ W_qkv, const float* __restrict__ W_eta_w,
                      const float* __restrict__ W_eta_b,
                      _Float16* __restrict__ Bp, float* __restrict__ s_vec,
                      float* __restrict__ cb_vec, float* __restrict__ we2,
                      float* __restrict__ scal)
{
  __shared__ float red1[256], red2[256];
  int n = blockIdx.x, t = threadIdx.x;
  float sp = 0.f, cp = 0.f;
  if (n < NCOL) {
    for (int h = t; h < HD; h += 256) {
      float w = (n < DD) ? sp_w[(size_t)h*DD + n] : W_qkv[(size_t)h*384 + 256 + (n-DD)];
      float g = ln_g[h], b = ln_b[h];
      Bp[(size_t)n*HD + h] = (_Float16)(g*w);
      sp += g*w; cp += b*w;
    }
  } else {
    for (int h = t; h < HD; h += 256) {
      float w = W_eta_w[h];
      float g = ln_g[h], b = ln_b[h];
      we2[h] = g*w;
      sp += g*w; cp += b*w;
    }
  }
  red1[t] = sp; red2[t] = cp;
  __syncthreads();
  for (int o = 128; o > 0; o >>= 1) {
    if (t < o) { red1[t] += red1[t+o]; red2[t] += red2[t+o]; }
    __syncthreads();
  }
  if (t == 0) {
    if (n < NCOL) {
      s_vec[n]  = red1[0];
      cb_vec[n] = red2[0] + ((n < DD) ? sp_b[n] : 0.f);
    } else {
      scal[0] = red1[0];
      scal[1] = red2[0] + W_eta_b[0];
      scal[2] = 0.f; scal[3] = 0.f;
    }
  }
}

// ---------------------------------------------------------------------------
// K01: fused LN-stats + GEMM + segment ops. One block per segment (b,s).
// A: fp32 H -> regs (stats side-sums) -> fp16 LDS (XOR chunk swizzle).
// B: Bp fp16 via global_load_lds (XOR source swizzle, linear LDS).
// MFMA 16x16x32 f16, BM=64 BN=256 BK=64; 4 waves each 64x64.
// Epilogue: LN affine; H_mem half kept in LDS -> summary softmax, Z, eta_seg,
// write-attn softmax (A_seg, Zeta); Q half staged in LDS -> coalesced write.
// ---------------------------------------------------------------------------
__launch_bounds__(256)
__global__ void k01(const float* __restrict__ H, const _Float16* __restrict__ Bp,
                    const float* __restrict__ s_vec, const float* __restrict__ cb_vec,
                    const float* __restrict__ we2, const float* __restrict__ scal,
                    const float* __restrict__ sum_q, const float* __restrict__ Mmat,
                    const float* __restrict__ temp,
                    float* __restrict__ Q_r, float* __restrict__ Zeta,
                    float* __restrict__ A_seg, float* __restrict__ eta_seg)
{
  __shared__ __align__(16) char pool[49152];
  __shared__ float smu[64], srs[64], seta[64];
  __shared__ float sq_s[128], w64_s[64], Zs[128], red_s[4];
  __shared__ float eta_sh_s;
  _Float16* sA  = (_Float16*)pool;            // 8 KB   [64 rows][8 chunks of 8]
  _Float16* sB  = (_Float16*)(pool + 8192);   // 32 KB  [256 rows][8 chunks]
  float*    we_s= (float*)(pool + 40960);     // 8 KB
  float*    sHm = (float*)pool;               // 33 KB epilogue alias (sA+sB region)

  int tid = threadIdx.x;
  int seg = blockIdx.x;
  int b   = seg >> 6;
  int m0  = seg * 64;
  int w = tid >> 6, lane = tid & 63, fcol = lane & 15, kq = lane >> 4;

  for (int i = tid; i < HD/4; i += 256)
    ((float4*)we_s)[i] = ((const float4*)we2)[i];
  if (tid < 128) sq_s[tid] = sum_q[tid];
  float scal0 = scal[0], scal1 = scal[1];

  // A loader: thread -> row r_l, 16-float strip starting at chunk cs
  int r_l = tid >> 2, cs = (tid & 3) * 2;
  const float* aptr = H + (size_t)(m0 + r_l)*HD + cs*8;
  // B loader: 8 glds slots
  int bn[8], bsl[8];
#pragma unroll
  for (int i = 0; i < 8; ++i) {
    int idx = i*256 + tid;
    bn[i]  = idx >> 3;
    bsl[i] = (idx & 7) ^ (bn[i] & 7);
  }

  f32x4 acc[4][4];
#pragma unroll
  for (int i = 0; i < 4; ++i)
#pragma unroll
    for (int j = 0; j < 4; ++j) acc[i][j] = (f32x4){0.f,0.f,0.f,0.f};
  float s1 = 0.f, s2 = 0.f, se = 0.f;

  float4 pa0 = *(const float4*)(aptr + 0);
  float4 pa1 = *(const float4*)(aptr + 4);
  float4 pa2 = *(const float4*)(aptr + 8);
  float4 pa3 = *(const float4*)(aptr + 12);

  for (int kt = 0; kt < 32; ++kt) {
    int k0 = kt*64;
    __syncthreads();
#pragma unroll
    for (int i = 0; i < 8; ++i)
      glds16(Bp + (size_t)bn[i]*HD + k0 + bsl[i]*8, sB + (size_t)(i*256 + tid)*8);
    // stage A + side stats
    {
      float v[16] = {pa0.x,pa0.y,pa0.z,pa0.w, pa1.x,pa1.y,pa1.z,pa1.w,
                     pa2.x,pa2.y,pa2.z,pa2.w, pa3.x,pa3.y,pa3.z,pa3.w};
      const float4* wv4 = (const float4*)(we_s + k0 + cs*8);
      float4 u0 = wv4[0], u1 = wv4[1], u2 = wv4[2], u3 = wv4[3];
      float uu[16] = {u0.x,u0.y,u0.z,u0.w, u1.x,u1.y,u1.z,u1.w,
                      u2.x,u2.y,u2.z,u2.w, u3.x,u3.y,u3.z,u3.w};
#pragma unroll
      for (int j = 0; j < 16; ++j) { s1 += v[j]; s2 += v[j]*v[j]; se += v[j]*uu[j]; }
      half8 h0, h1;
#pragma unroll
      for (int j = 0; j < 8; ++j) { h0[j] = (_Float16)v[j]; h1[j] = (_Float16)v[8+j]; }
      *(half8*)&sA[r_l*64 + ((cs  ) ^ (r_l & 7))*8] = h0;
      *(half8*)&sA[r_l*64 + ((cs+1) ^ (r_l & 7))*8] = h1;
    }
    __syncthreads();
    if (kt+1 < 32) {
      const float* ap = aptr + (kt+1)*64;
      pa0 = *(const float4*)(ap + 0);
      pa1 = *(const float4*)(ap + 4);
      pa2 = *(const float4*)(ap + 8);
      pa3 = *(const float4*)(ap + 12);
    }
#pragma unroll
    for (int ks = 0; ks < 2; ++ks) {
      half8 af[4], bf[4];
#pragma unroll
      for (int rt = 0; rt < 4; ++rt) {
        int r = rt*16 + fcol;
        int ch = (ks*4 + kq) ^ (r & 7);
        af[rt] = *(half8*)&sA[r*64 + ch*8];
      }
#pragma unroll
      for (int ct = 0; ct < 4; ++ct) {
        int n = w*64 + ct*16 + fcol;
        int ch = (ks*4 + kq) ^ (n & 7);
        bf[ct] = *(half8*)&sB[n*64 + ch*8];
      }
#pragma unroll
      for (int rt = 0; rt < 4; ++rt)
#pragma unroll
        for (int ct = 0; ct < 4; ++ct)
          acc[rt][ct] = __builtin_amdgcn_mfma_f32_16x16x32_f16(af[rt], bf[ct], acc[rt][ct], 0,0,0);
    }
  }

  // row stats: reduce across the 4 strip-threads of each row (same wave)
  s1 += __shfl_xor(s1, 1); s1 += __shfl_xor(s1, 2);
  s2 += __shfl_xor(s2, 1); s2 += __shfl_xor(s2, 2);
  se += __shfl_xor(se, 1); se += __shfl_xor(se, 2);
  if ((tid & 3) == 0) {
    int row = tid >> 2;
    float mu   = s1 * (1.f/HD);
    float var  = s2 * (1.f/HD) - mu*mu;
    float rstd = rsqrtf(var + 1e-5f);
    smu[row] = mu; srs[row] = rstd;
    seta[row] = rstd*(se - mu*scal0) + scal1;
  }
  __syncthreads();   // stats visible; last MFMA reads done -> pool reusable

  // epilogue: H_mem half (cols 0..127) -> sHm
  if (w < 2) {
#pragma unroll
    for (int ct = 0; ct < 4; ++ct) {
      int n = w*64 + ct*16 + fcol;
      float sn = s_vec[n], cbn = cb_vec[n];
#pragma unroll
      for (int rt = 0; rt < 4; ++rt)
#pragma unroll
        for (int r = 0; r < 4; ++r) {
          int m = rt*16 + kq*4 + r;
          sHm[m*132 + n] = srs[m]*(acc[rt][ct][r] - smu[m]*sn) + cbn;
        }
    }
  }
  __syncthreads();   // sHm ready

  // summary softmax (wave 0) / eta_seg (wave 1)
  if (w == 0) {
    float sc = 0.f;
    const float4* hrow = (const float4*)&sHm[lane*132];
#pragma unroll
    for (int d4 = 0; d4 < 32; ++d4) {
      float4 hv = hrow[d4];
      float4 qv = *(const float4*)&sq_s[d4*4];
      sc += hv.x*qv.x + hv.y*qv.y + hv.z*qv.z + hv.w*qv.w;
    }
    sc *= SCALE_D;
    float mx = sc;
    for (int o = 32; o > 0; o >>= 1) mx = fmaxf(mx, __shfl_xor(mx, o));
    float e = __expf(sc - mx);
    float sm = e;
    for (int o = 32; o > 0; o >>= 1) sm += __shfl_xor(sm, o);
    w64_s[lane] = e / sm;
  } else if (w == 1) {
    float ev = seta[lane];
    for (int o = 32; o > 0; o >>= 1) ev = fmaxf(ev, __shfl_xor(ev, o));
    if (lane == 0) { float es = sigmf(ev); eta_sh_s = es; eta_seg[seg] = es; }
  }
  __syncthreads();   // w64_s, eta_sh_s ready

  // Z[d] + Zeta
  if (tid < 128) {
    float z = 0.f;
    for (int l = 0; l < 64; ++l) z += w64_s[l]*sHm[l*132 + tid];
    Zs[tid] = z;
    Zeta[(size_t)seg*DD + tid] = z * eta_sh_s;
  }
  __syncthreads();   // Zs ready; sHm free

  // Q half (cols 128..255) -> sHm buffer (staging), waves 2,3
  if (w >= 2) {
#pragma unroll
    for (int ct = 0; ct < 4; ++ct) {
      int n  = w*64 + ct*16 + fcol;   // 128..255
      int nq = n - 128;
      float sn = s_vec[n], cbn = cb_vec[n];
#pragma unroll
      for (int rt = 0; rt < 4; ++rt)
#pragma unroll
        for (int r = 0; r < 4; ++r) {
          int m = rt*16 + kq*4 + r;
          sHm[m*132 + nq] = srs[m]*(acc[rt][ct][r] - smu[m]*sn) + cbn;
        }
    }
  }
  // write-attn scores (waves 0,1 in parallel with Q staging)
  float sc2 = 0.f;
  if (tid < 128) {
    const float4* mrow = (const float4*)(Mmat + ((size_t)b*DD + tid)*DD);
#pragma unroll
    for (int d4 = 0; d4 < 32; ++d4) {
      float4 mv = mrow[d4];
      sc2 += mv.x*Zs[d4*4] + mv.y*Zs[d4*4+1] + mv.z*Zs[d4*4+2] + mv.w*Zs[d4*4+3];
    }
    sc2 *= SCALE_D * __expf(temp[0]);
  }
  __syncthreads();   // sQ staging complete

  // coalesced Q_r writes
#pragma unroll
  for (int j = 0; j < 8; ++j) {
    int idx = j*256 + tid;
    int row = idx >> 5, c4 = (idx & 31)*4;
    *(float4*)&Q_r[(size_t)(m0 + row)*DD + c4] = *(float4*)&sHm[row*132 + c4];
  }
  // softmax over 128 keys (2 waves)
  float ev2 = 0.f;
  if (tid < 128) {
    float mx = sc2;
    for (int o = 32; o > 0; o >>= 1) mx = fmaxf(mx, __shfl_xor(mx, o));
    if (lane == 0) red_s[w] = mx;
  }
  __syncthreads();
  if (tid < 128) {
    float mx = fmaxf(red_s[0], red_s[1]);
    ev2 = __expf(sc2 - mx);
    float sm = ev2;
    for (int o = 32; o > 0; o >>= 1) sm += __shfl_xor(sm, o);
    if (lane == 0) red_s[2 + w] = sm;
  }
  __syncthreads();
  if (tid < 128) {
    float sm = red_s[2] + red_s[3];
    A_seg[(size_t)seg*DD + tid] = ev2 / sm;
  }
}

// ---------------------------------------------------------------------------
// K2b: DeltaM (k-chunk of 32 per block), M_new, row rnorms, norm_sq atomic.
// ---------------------------------------------------------------------------
__global__ void k2b(const float* __restrict__ A_seg, const float* __restrict__ Zeta,
                    const float* __restrict__ eta_seg, const float* __restrict__ Mmat,
                    const float* __restrict__ eta_ch,
                    float* __restrict__ M_new, float* __restrict__ rns_arr,
                    float* __restrict__ scal)
{
  __shared__ float As[64][33];
  __shared__ __align__(16) float Zsl[64*128];
  __shared__ float rowp[32][8];
  __shared__ float eta_av;
  __shared__ float redb[4];
  int tid = threadIdx.x;
  int b = blockIdx.x >> 2, kq = blockIdx.x & 3;
  for (int i = tid; i < 64*32; i += 256) {
    int s = i >> 5, j = i & 31;
    As[s][j] = A_seg[((size_t)b*SSEG + s)*DD + kq*32 + j];
  }
  const float4* z4 = (const float4*)(Zeta + (size_t)b*SSEG*DD);
  float4* zs4 = (float4*)Zsl;
  for (int i = tid; i < 64*32; i += 256) zs4[i] = z4[i];
  if (tid < 64) {
    float ev = eta_seg[(size_t)b*SSEG + tid];
    for (int o=32;o>0;o>>=1) ev += __shfl_xor(ev, o);
    if (tid == 0) eta_av = ev * (1.f/SSEG);
  }
  __syncthreads();
  int kl = tid & 31, dg = tid >> 5;
  int k = kq*32 + kl, d0 = dg*16;
  float dm[16];
#pragma unroll
  for (int j=0;j<16;j++) dm[j]=0.f;
  for (int s = 0; s < 64; ++s) {
    float a = As[s][kl];
    const float* zr = &Zsl[s*128 + d0];
#pragma unroll
    for (int j=0;j<16;j++) dm[j] += a * zr[j];
  }
  float nsq = 0.f;
#pragma unroll
  for (int j=0;j<16;j++) nsq += dm[j]*dm[j];
  float eav = eta_av;
  float mn[16];
  float ss = 0.f;
#pragma unroll
  for (int j=0;j<16;j++) {
    int d = d0 + j;
    float gate = eav * sigmf(eta_ch[d]);
    float v = (1.f - gate)*Mmat[((size_t)b*DD + k)*DD + d] + dm[j]*(1.f/SSEG);
    mn[j] = v; ss += v*v;
  }
#pragma unroll
  for (int j=0;j<16;j+=4) {
    float4 v4; v4.x=mn[j]; v4.y=mn[j+1]; v4.z=mn[j+2]; v4.w=mn[j+3];
    *(float4*)&M_new[((size_t)b*DD + k)*DD + d0 + j] = v4;
  }
  rowp[kl][dg] = ss;
  for (int o=1;o<64;o<<=1) nsq += __shfl_xor(nsq, o);
  if ((tid&63)==0) redb[tid>>6] = nsq;
  __syncthreads();
  if (tid == 0) atomicAdd(&scal[2], redb[0]+redb[1]+redb[2]+redb[3]);
  if (tid < 32) {
    float t2 = 0.f;
#pragma unroll
    for (int g=0; g<8; ++g) t2 += rowp[tid][g];
    float nrm = sqrtf(t2);
    rns_arr[(size_t)b*DD + kq*32 + tid] = 1.f / fmaxf(nrm, 1e-12f);
  }
}

// ---------------------------------------------------------------------------
// K2d: diversity loss partials.
// ---------------------------------------------------------------------------
__global__ void k2d(const float* __restrict__ M_new, const float* __restrict__ rns_arr,
                    float* __restrict__ scal)
{
  __shared__ float kr[4][128];
  __shared__ float redb[4];
  int tid = threadIdx.x;
  int b = blockIdx.x >> 5, kq = blockIdx.x & 31;
  for (int i = tid; i < 4*128; i += 256) {
    int ki = i >> 7, d = i & 127;
    kr[ki][d] = M_new[((size_t)b*DD + kq*4 + ki)*DD + d];
  }
  __syncthreads();
  int j = tid & 127, kh = tid >> 7;
  const float* mj = &M_new[((size_t)b*DD + j)*DD];
  float rj = rns_arr[(size_t)b*DD + j];
  float dv = 0.f;
#pragma unroll
  for (int ki2 = 0; ki2 < 2; ++ki2) {
    int kil = kh*2 + ki2;
    int kk = kq*4 + kil;
    float dot = 0.f;
    for (int d = 0; d < 128; d += 4) {
      float4 a = *(const float4*)(mj + d);
      dot += a.x*kr[kil][d] + a.y*kr[kil][d+1] + a.z*kr[kil][d+2] + a.w*kr[kil][d+3];
    }
    if (kk != j) {
      float sv = dot * rj * rns_arr[(size_t)b*DD + kk];
      dv += sv*sv;
    }
  }
  for (int o=1;o<64;o<<=1) dv += __shfl_xor(dv, o);
  if ((tid&63)==0) redb[tid>>6] = dv;
  __syncthreads();
  if (tid==0) atomicAdd(&scal[3], redb[0]+redb[1]+redb[2]+redb[3]);
}

// ---------------------------------------------------------------------------
// K3: read attention via MFMA fp16 (fp32 softmax/accum).
// ---------------------------------------------------------------------------
__launch_bounds__(256, 1)
__global__ void k3(const float* __restrict__ Q_r, const float* __restrict__ M_new,
                   const float* __restrict__ scal, float* __restrict__ out)
{
  __shared__ __align__(16) _Float16 Mq[128*132];  // [key][d]   (QK B-frags)
  __shared__ __align__(16) _Float16 Mt[128*136];  // [d][key]   (PV B-frags)
  __shared__ __align__(16) _Float16 Ps[64*132];   // [token][key] (PV A-frags)
  int tid = threadIdx.x;
  int b = blockIdx.x >> 6, tile = blockIdx.x & 63;
  int t0 = tile*64;
  if (blockIdx.x == 0 && tid == 0) {
    float loss = 0.01f*(scal[2]*(1.f/SSEG)) + 0.1f*(scal[3]*(1.f/(BB*DD*DD)));
    out[(size_t)MT*DD] = loss;
  }
  const float4* m4 = (const float4*)(M_new + (size_t)b*DD*DD);
#pragma unroll
  for (int it = 0; it < 4; ++it) {
    int sb = it*256 + tid;
    int rb = sb & 31, cb = sb >> 5;
    int r0 = rb*4, c0 = cb*4;
    float a[4][4];
#pragma unroll
    for (int j = 0; j < 4; ++j) {
      float4 v = m4[(size_t)(r0+j)*32 + cb];
      a[j][0]=v.x; a[j][1]=v.y; a[j][2]=v.z; a[j][3]=v.w;
    }
#pragma unroll
    for (int j = 0; j < 4; ++j) {
      half4v h; h.x=(_Float16)a[j][0]; h.y=(_Float16)a[j][1];
                h.z=(_Float16)a[j][2]; h.w=(_Float16)a[j][3];
      *(half4v*)&Mq[(r0+j)*132 + c0] = h;
    }
#pragma unroll
    for (int j2 = 0; j2 < 4; ++j2) {
      half4v h; h.x=(_Float16)a[0][j2]; h.y=(_Float16)a[1][j2];
                h.z=(_Float16)a[2][j2]; h.w=(_Float16)a[3][j2];
      *(half4v*)&Mt[(c0+j2)*136 + r0] = h;
    }
  }
  int w = tid >> 6, lane = tid & 63;
  int fcol = lane & 15, kq = lane >> 4;
  int tokA = t0 + w*16 + fcol;
  size_t qbase = ((size_t)b*TT + tokA)*DD;
  half8 af[4];
#pragma unroll
  for (int ks = 0; ks < 4; ++ks) {
    float4 q0 = *(const float4*)&Q_r[qbase + ks*32 + kq*8];
    float4 q1 = *(const float4*)&Q_r[qbase + ks*32 + kq*8 + 4];
    half8 h;
    h[0]=(_Float16)q0.x; h[1]=(_Float16)q0.y; h[2]=(_Float16)q0.z; h[3]=(_Float16)q0.w;
    h[4]=(_Float16)q1.x; h[5]=(_Float16)q1.y; h[6]=(_Float16)q1.z; h[7]=(_Float16)q1.w;
    af[ks] = h;
  }
  __syncthreads();
  f32x4 sacc[8];
#pragma unroll
  for (int nt = 0; nt < 8; ++nt) sacc[nt] = (f32x4){0.f,0.f,0.f,0.f};
#pragma unroll
  for (int nt = 0; nt < 8; ++nt)
#pragma unroll
    for (int ks = 0; ks < 4; ++ks) {
      half8 bf = *(half8*)&Mq[(nt*16 + fcol)*132 + ks*32 + kq*8];
      sacc[nt] = __builtin_amdgcn_mfma_f32_16x16x32_f16(af[ks], bf, sacc[nt], 0,0,0);
    }
#pragma unroll
  for (int nt = 0; nt < 8; ++nt)
#pragma unroll
    for (int r = 0; r < 4; ++r) sacc[nt][r] *= 2.f;
  float mx[4], sm[4];
#pragma unroll
  for (int r = 0; r < 4; ++r) {
    float m = sacc[0][r];
#pragma unroll
    for (int nt = 1; nt < 8; ++nt) m = fmaxf(m, sacc[nt][r]);
#pragma unroll
    for (int o = 1; o < 16; o <<= 1) m = fmaxf(m, __shfl_xor(m, o));
    mx[r] = m;
  }
#pragma unroll
  for (int r = 0; r < 4; ++r) sm[r] = 0.f;
#pragma unroll
  for (int nt = 0; nt < 8; ++nt)
#pragma unroll
    for (int r = 0; r < 4; ++r) {
      float e = __expf(sacc[nt][r] - mx[r]);
      sacc[nt][r] = e; sm[r] += e;
    }
#pragma unroll
  for (int r = 0; r < 4; ++r) {
    float s = sm[r];
#pragma unroll
    for (int o = 1; o < 16; o <<= 1) s += __shfl_xor(s, o);
    sm[r] = 1.f / s;
  }
#pragma unroll
  for (int nt = 0; nt < 8; ++nt)
#pragma unroll
    for (int r = 0; r < 4; ++r) {
      int tk = w*16 + kq*4 + r;
      Ps[tk*132 + nt*16 + fcol] = (_Float16)(sacc[nt][r]*sm[r]);
    }
  __syncthreads();
  half8 pf[4];
#pragma unroll
  for (int ks = 0; ks < 4; ++ks)
    pf[ks] = *(half8*)&Ps[(w*16 + fcol)*132 + ks*32 + kq*8];
  f32x4 cacc[8];
#pragma unroll
  for (int nt = 0; nt < 8; ++nt) cacc[nt] = (f32x4){0.f,0.f,0.f,0.f};
#pragma unroll
  for (int nt = 0; nt < 8; ++nt)
#pragma unroll
    for (int ks = 0; ks < 4; ++ks) {
      half8 bf = *(half8*)&Mt[(nt*16 + fcol)*136 + ks*32 + kq*8];
      cacc[nt] = __builtin_amdgcn_mfma_f32_16x16x32_f16(pf[ks], bf, cacc[nt], 0,0,0);
    }
#pragma unroll
  for (int nt = 0; nt < 8; ++nt)
#pragma unroll
    for (int r = 0; r < 4; ++r) {
      int tk = t0 + w*16 + kq*4 + r;
      out[((size_t)b*TT + tk)*DD + nt*16 + fcol] = cacc[nt][r];
    }
}

// ---------------------------------------------------------------------------
extern "C" void kernel_launch(void* const* d_in, const int* in_sizes, int n_in,
                              void* d_out, int out_size, void* d_ws, size_t ws_size,
                              hipStream_t stream)
{
  (void)in_sizes; (void)n_in; (void)out_size; (void)ws_size;
  const float* H       = (const float*)d_in[0];
  const float* Mmat    = (const float*)d_in[1];
  const float* ln_g    = (const float*)d_in[2];
  const float* ln_b    = (const float*)d_in[3];
  const float* W_eta_w = (const float*)d_in[4];
  const float* W_eta_b = (const float*)d_in[5];
  const float* sum_q   = (const float*)d_in[6];
  const float* sp_w    = (const float*)d_in[7];
  const float* sp_b    = (const float*)d_in[8];
  const float* eta_ch  = (const float*)d_in[9];
  const float* temp    = (const float*)d_in[10];
  const float* W_qkv   = (const float*)d_in[11];
  float* out           = (float*)d_out;

  char* wsb = (char*)d_ws;
  size_t off = 0;
  auto alloc = [&](size_t bytes) -> void* {
    void* p = wsb + off;
    off = (off + bytes + 255) & ~(size_t)255;
    return p;
  };
  _Float16* Bp   = (_Float16*)alloc((size_t)NCOL*HD*2);
  float* s_vec   = (float*)alloc(NCOL*4);
  float* cb_vec  = (float*)alloc(NCOL*4);
  float* we2     = (float*)alloc(HD*4);
  float* scal    = (float*)alloc(4*4);
  float* Q_r     = (float*)alloc((size_t)MT*DD*4);
  float* Zeta    = (float*)alloc((size_t)BB*SSEG*DD*4);
  float* A_seg   = (float*)alloc((size_t)BB*SSEG*DD*4);
  float* eta_seg = (float*)alloc((size_t)BB*SSEG*4);
  float* M_new   = (float*)alloc((size_t)BB*DD*DD*4);
  float* rns_arr = (float*)alloc((size_t)BB*DD*4);

  hipLaunchKernelGGL(k_pre, dim3(NCOL+1), dim3(256), 0, stream,
                     ln_g, ln_b, sp_w, sp_b, W_qkv, W_eta_w, W_eta_b,
                     Bp, s_vec, cb_vec, we2, scal);
  hipLaunchKernelGGL(k01, dim3(MT/64), dim3(256), 0, stream,
                     H, Bp, s_vec, cb_vec, we2, scal, sum_q, Mmat, temp,
                     Q_r, Zeta, A_seg, eta_seg);
  hipLaunchKernelGGL(k2b, dim3(16), dim3(256), 0, stream,
                     A_seg, Zeta, eta_seg, Mmat, eta_ch, M_new, rns_arr, scal);
  hipLaunchKernelGGL(k2d, dim3(128), dim3(256), 0, stream,
                     M_new, rns_arr, scal);
  hipLaunchKernelGGL(k3, dim3(256), dim3(256), 0, stream,
                     Q_r, M_new, scal, out);
}

// Round 7
// 289.120 us; speedup vs baseline: 1.6850x; 1.0046x over previous
//
#include <hip/hip_runtime.h>
#include <hip/hip_bf16.h>
#include <math.h>

#define HD   2048
#define DD   128
#define TT   4096
#define BB   4
#define MT   (BB*TT)     // 16384 tokens
#define LSEG 64
#define SSEG 64
#define NCOL 256
#define SCALE_D 0.088388347648318447f  // 1/sqrt(128)

typedef _Float16 half8 __attribute__((ext_vector_type(8)));
typedef _Float16 half4v __attribute__((ext_vector_type(4)));
typedef float    f32x4 __attribute__((ext_vector_type(4)));

__device__ __forceinline__ float sigmf(float x){ return 1.f/(1.f+__expf(-x)); }

__device__ __forceinline__ void glds16(const void* g, void* l) {
  __builtin_amdgcn_global_load_lds(
      (const __attribute__((address_space(1))) unsigned int*)g,
      (__attribute__((address_space(3))) unsigned int*)l, 16, 0, 0);
}

// ---------------------------------------------------------------------------
// K_pre: pack B' = g (.) [sp_w | W_q] as fp16, n-major [256][2048], LINEAR
// storage (R5-proven). Per-col sums s_n, cb_n; we2 = g*w_eta;
// scal = {s_eta, cb_eta, 0, 0}
// ---------------------------------------------------------------------------
__global__ void k_pre(const float* __restrict__ ln_g, const float* __restrict__ ln_b,
                      const float* __restrict__ sp_w, const float* __restrict__ sp_b,
                      const float* __restrict__ W_qkv, const float* __restrict__ W_eta_w,
                      const float* __restrict__ W_eta_b,
                      _Float16* __restrict__ Bp, float* __restrict__ s_vec,
                      float* __restrict__ cb_vec, float* __restrict__ we2,
                      float* __restrict__ scal)
{
  __shared__ float red1[256], red2[256];
  int n = blockIdx.x, t = threadIdx.x;
  float sp = 0.f, cp = 0.f;
  if (n < NCOL) {
    for (int h = t; h < HD; h += 256) {
      float w = (n < DD) ? sp_w[(size_t)h*DD + n] : W_qkv[(size_t)h*384 + 256 + (n-DD)];
      float g = ln_g[h], b = ln_b[h];
      Bp[(size_t)n*HD + h] = (_Float16)(g*w);
      sp += g*w; cp += b*w;
    }
  } else {
    for (int h = t; h < HD; h += 256) {
      float w = W_eta_w[h];
      float g = ln_g[h], b = ln_b[h];
      we2[h] = g*w;
      sp += g*w; cp += b*w;
    }
  }
  red1[t] = sp; red2[t] = cp;
  __syncthreads();
  for (int o = 128; o > 0; o >>= 1) {
    if (t < o) { red1[t] += red1[t+o]; red2[t] += red2[t+o]; }
    __syncthreads();
  }
  if (t == 0) {
    if (n < NCOL) {
      s_vec[n]  = red1[0];
      cb_vec[n] = red2[0] + ((n < DD) ? sp_b[n] : 0.f);
    } else {
      scal[0] = red1[0];
      scal[1] = red2[0] + W_eta_b[0];
      scal[2] = 0.f; scal[3] = 0.f;
    }
  }
}

// ---------------------------------------------------------------------------
// K01: fused LN-stats + GEMM + segment ops. Grid 512 = 256 segments x 2
// n-halves (2 blocks/CU). BM=64 BN=128 BK=64, 4 waves each 64x32.
// ntile0: H_mem cols -> LDS -> segment ops (summary softmax, Z, eta, A_seg).
// ntile1: Q cols -> LDS -> coalesced Q_r write.
// A: fp32 H -> regs (stats side-sums) -> fp16 LDS (XOR chunk swizzle).
// B: linear Bp via glds with per-lane XOR'd SOURCE offsets (R5-proven).
// ---------------------------------------------------------------------------
__launch_bounds__(256, 2)
__global__ void k01(const float* __restrict__ H, const _Float16* __restrict__ Bp,
                    const float* __restrict__ s_vec, const float* __restrict__ cb_vec,
                    const float* __restrict__ we2, const float* __restrict__ scal,
                    const float* __restrict__ sum_q, const float* __restrict__ Mmat,
                    const float* __restrict__ temp,
                    float* __restrict__ Q_r, float* __restrict__ Zeta,
                    float* __restrict__ A_seg, float* __restrict__ eta_seg)
{
  __shared__ __align__(16) char pool[33792];   // sA(8K)+sB(16K) | sHm 64x132 f32
  __shared__ float we_s[HD];                   // 8 KB
  __shared__ float smu[64], srs[64], seta[64];
  __shared__ float sq_s[128], w64_s[64], Zs[128], red_s[4];
  __shared__ float eta_sh_s;
  _Float16* sA  = (_Float16*)pool;             // [64 rows][8 chunks of 8]
  _Float16* sB  = (_Float16*)(pool + 8192);    // [128 rows][8 chunks]
  float*    sHm = (float*)pool;                // epilogue alias

  int tid = threadIdx.x;
  int seg = blockIdx.x >> 1, ntile = blockIdx.x & 1;
  int b   = seg >> 6;
  int m0  = seg * 64;
  int n0  = ntile * 128;
  int w = tid >> 6, lane = tid & 63, fcol = lane & 15, kq = lane >> 4;

  for (int i = tid; i < HD/4; i += 256)
    ((float4*)we_s)[i] = ((const float4*)we2)[i];
  if (tid < 128) sq_s[tid] = sum_q[tid];
  float scal0 = scal[0], scal1 = scal[1];

  // A loader: thread -> row r_l, 16-float strip starting at chunk cs
  int r_l = tid >> 2, cs = (tid & 3) * 2;
  const float* aptr = H + (size_t)(m0 + r_l)*HD + cs*8;
  // B loader: 4 glds slots, XOR'd source chunk (dest linear)
  int bn[4], bsl[4];
#pragma unroll
  for (int i = 0; i < 4; ++i) {
    int idx = i*256 + tid;
    bn[i]  = idx >> 3;
    bsl[i] = (idx & 7) ^ (bn[i] & 7);
  }

  f32x4 acc[4][2];
#pragma unroll
  for (int i = 0; i < 4; ++i)
#pragma unroll
    for (int j = 0; j < 2; ++j) acc[i][j] = (f32x4){0.f,0.f,0.f,0.f};
  float s1 = 0.f, s2 = 0.f, se = 0.f;

  float4 pa0 = *(const float4*)(aptr + 0);
  float4 pa1 = *(const float4*)(aptr + 4);
  float4 pa2 = *(const float4*)(aptr + 8);
  float4 pa3 = *(const float4*)(aptr + 12);

  for (int kt = 0; kt < 32; ++kt) {
    int k0 = kt*64;
    __syncthreads();
#pragma unroll
    for (int i = 0; i < 4; ++i)
      glds16(Bp + (size_t)(n0 + bn[i])*HD + k0 + bsl[i]*8,
             sB + (size_t)(i*256 + tid)*8);
    // stage A + side stats
    {
      float v[16] = {pa0.x,pa0.y,pa0.z,pa0.w, pa1.x,pa1.y,pa1.z,pa1.w,
                     pa2.x,pa2.y,pa2.z,pa2.w, pa3.x,pa3.y,pa3.z,pa3.w};
      const float4* wv4 = (const float4*)(we_s + k0 + cs*8);
      float4 u0 = wv4[0], u1 = wv4[1], u2 = wv4[2], u3 = wv4[3];
      float uu[16] = {u0.x,u0.y,u0.z,u0.w, u1.x,u1.y,u1.z,u1.w,
                      u2.x,u2.y,u2.z,u2.w, u3.x,u3.y,u3.z,u3.w};
#pragma unroll
      for (int j = 0; j < 16; ++j) { s1 += v[j]; s2 += v[j]*v[j]; se += v[j]*uu[j]; }
      half8 h0, h1;
#pragma unroll
      for (int j = 0; j < 8; ++j) { h0[j] = (_Float16)v[j]; h1[j] = (_Float16)v[8+j]; }
      *(half8*)&sA[r_l*64 + ((cs  ) ^ (r_l & 7))*8] = h0;
      *(half8*)&sA[r_l*64 + ((cs+1) ^ (r_l & 7))*8] = h1;
    }
    __syncthreads();
    if (kt+1 < 32) {
      const float* ap = aptr + (kt+1)*64;
      pa0 = *(const float4*)(ap + 0);
      pa1 = *(const float4*)(ap + 4);
      pa2 = *(const float4*)(ap + 8);
      pa3 = *(const float4*)(ap + 12);
    }
#pragma unroll
    for (int ks = 0; ks < 2; ++ks) {
      half8 af[4], bf[2];
#pragma unroll
      for (int rt = 0; rt < 4; ++rt) {
        int r = rt*16 + fcol;
        int ch = (ks*4 + kq) ^ (r & 7);
        af[rt] = *(half8*)&sA[r*64 + ch*8];
      }
#pragma unroll
      for (int ct = 0; ct < 2; ++ct) {
        int n = w*32 + ct*16 + fcol;     // local col; (n0+n)&7 == n&7
        int ch = (ks*4 + kq) ^ (n & 7);
        bf[ct] = *(half8*)&sB[n*64 + ch*8];
      }
#pragma unroll
      for (int rt = 0; rt < 4; ++rt)
#pragma unroll
        for (int ct = 0; ct < 2; ++ct)
          acc[rt][ct] = __builtin_amdgcn_mfma_f32_16x16x32_f16(af[rt], bf[ct], acc[rt][ct], 0,0,0);
    }
  }

  // row stats: reduce across the 4 strip-threads of each row (same wave)
  s1 += __shfl_xor(s1, 1); s1 += __shfl_xor(s1, 2);
  s2 += __shfl_xor(s2, 1); s2 += __shfl_xor(s2, 2);
  se += __shfl_xor(se, 1); se += __shfl_xor(se, 2);
  if ((tid & 3) == 0) {
    int row = tid >> 2;
    float mu   = s1 * (1.f/HD);
    float var  = s2 * (1.f/HD) - mu*mu;
    float rstd = rsqrtf(var + 1e-5f);
    smu[row] = mu; srs[row] = rstd;
    seta[row] = rstd*(se - mu*scal0) + scal1;
  }
  __syncthreads();   // stats visible; MFMA reads done -> pool reusable

  // epilogue: LN affine -> sHm (local cols 0..127)
#pragma unroll
  for (int ct = 0; ct < 2; ++ct) {
    int nl = w*32 + ct*16 + fcol;
    float sn = s_vec[n0 + nl], cbn = cb_vec[n0 + nl];
#pragma unroll
    for (int rt = 0; rt < 4; ++rt)
#pragma unroll
      for (int r = 0; r < 4; ++r) {
        int m = rt*16 + kq*4 + r;
        sHm[m*132 + nl] = srs[m]*(acc[rt][ct][r] - smu[m]*sn) + cbn;
      }
  }
  __syncthreads();   // sHm ready

  if (ntile == 1) {
    // coalesced Q_r writes
#pragma unroll
    for (int j = 0; j < 8; ++j) {
      int idx = j*256 + tid;
      int row = idx >> 5, c4 = (idx & 31)*4;
      *(float4*)&Q_r[(size_t)(m0 + row)*DD + c4] = *(float4*)&sHm[row*132 + c4];
    }
    return;
  }

  // ---- ntile0: segment ops on H_mem in LDS ----
  // summary softmax (wave 0) / eta_seg (wave 1)
  if (w == 0) {
    float sc = 0.f;
    const float4* hrow = (const float4*)&sHm[lane*132];
#pragma unroll
    for (int d4 = 0; d4 < 32; ++d4) {
      float4 hv = hrow[d4];
      float4 qv = *(const float4*)&sq_s[d4*4];
      sc += hv.x*qv.x + hv.y*qv.y + hv.z*qv.z + hv.w*qv.w;
    }
    sc *= SCALE_D;
    float mx = sc;
    for (int o = 32; o > 0; o >>= 1) mx = fmaxf(mx, __shfl_xor(mx, o));
    float e = __expf(sc - mx);
    float sm = e;
    for (int o = 32; o > 0; o >>= 1) sm += __shfl_xor(sm, o);
    w64_s[lane] = e / sm;
  } else if (w == 1) {
    float ev = seta[lane];
    for (int o = 32; o > 0; o >>= 1) ev = fmaxf(ev, __shfl_xor(ev, o));
    if (lane == 0) { float es = sigmf(ev); eta_sh_s = es; eta_seg[seg] = es; }
  }
  __syncthreads();   // w64_s, eta_sh_s ready

  // Z[d] + Zeta
  if (tid < 128) {
    float z = 0.f;
    for (int l = 0; l < 64; ++l) z += w64_s[l]*sHm[l*132 + tid];
    Zs[tid] = z;
    Zeta[(size_t)seg*DD + tid] = z * eta_sh_s;
  }
  __syncthreads();   // Zs ready

  // write-attn scores over K=128 + softmax (flat barriers, R5-proven form)
  float sc2 = 0.f;
  if (tid < 128) {
    const float4* mrow = (const float4*)(Mmat + ((size_t)b*DD + tid)*DD);
#pragma unroll
    for (int d4 = 0; d4 < 32; ++d4) {
      float4 mv = mrow[d4];
      sc2 += mv.x*Zs[d4*4] + mv.y*Zs[d4*4+1] + mv.z*Zs[d4*4+2] + mv.w*Zs[d4*4+3];
    }
    sc2 *= SCALE_D * __expf(temp[0]);
    float mx = sc2;
    for (int o = 32; o > 0; o >>= 1) mx = fmaxf(mx, __shfl_xor(mx, o));
    if (lane == 0) red_s[w] = mx;
  }
  __syncthreads();
  float ev2 = 0.f;
  if (tid < 128) {
    float mx = fmaxf(red_s[0], red_s[1]);
    ev2 = __expf(sc2 - mx);
    float sm = ev2;
    for (int o = 32; o > 0; o >>= 1) sm += __shfl_xor(sm, o);
    if (lane == 0) red_s[2 + w] = sm;
  }
  __syncthreads();
  if (tid < 128) {
    float smt = red_s[2] + red_s[3];
    A_seg[(size_t)seg*DD + tid] = ev2 / smt;
  }
}

// ---------------------------------------------------------------------------
// K2b: DeltaM (k-chunk of 32 per block), M_new, row rnorms, norm_sq atomic.
// ---------------------------------------------------------------------------
__global__ void k2b(const float* __restrict__ A_seg, const float* __restrict__ Zeta,
                    const float* __restrict__ eta_seg, const float* __restrict__ Mmat,
                    const float* __restrict__ eta_ch,
                    float* __restrict__ M_new, float* __restrict__ rns_arr,
                    float* __restrict__ scal)
{
  __shared__ float As[64][33];
  __shared__ __align__(16) float Zsl[64*128];
  __shared__ float rowp[32][8];
  __shared__ float eta_av;
  __shared__ float redb[4];
  int tid = threadIdx.x;
  int b = blockIdx.x >> 2, kq = blockIdx.x & 3;
  for (int i = tid; i < 64*32; i += 256) {
    int s = i >> 5, j = i & 31;
    As[s][j] = A_seg[((size_t)b*SSEG + s)*DD + kq*32 + j];
  }
  const float4* z4 = (const float4*)(Zeta + (size_t)b*SSEG*DD);
  float4* zs4 = (float4*)Zsl;
  for (int i = tid; i < 64*32; i += 256) zs4[i] = z4[i];
  if (tid < 64) {
    float ev = eta_seg[(size_t)b*SSEG + tid];
    for (int o=32;o>0;o>>=1) ev += __shfl_xor(ev, o);
    if (tid == 0) eta_av = ev * (1.f/SSEG);
  }
  __syncthreads();
  int kl = tid & 31, dg = tid >> 5;
  int k = kq*32 + kl, d0 = dg*16;
  float dm[16];
#pragma unroll
  for (int j=0;j<16;j++) dm[j]=0.f;
  for (int s = 0; s < 64; ++s) {
    float a = As[s][kl];
    const float* zr = &Zsl[s*128 + d0];
#pragma unroll
    for (int j=0;j<16;j++) dm[j] += a * zr[j];
  }
  float nsq = 0.f;
#pragma unroll
  for (int j=0;j<16;j++) nsq += dm[j]*dm[j];
  float eav = eta_av;
  float mn[16];
  float ss = 0.f;
#pragma unroll
  for (int j=0;j<16;j++) {
    int d = d0 + j;
    float gate = eav * sigmf(eta_ch[d]);
    float v = (1.f - gate)*Mmat[((size_t)b*DD + k)*DD + d] + dm[j]*(1.f/SSEG);
    mn[j] = v; ss += v*v;
  }
#pragma unroll
  for (int j=0;j<16;j+=4) {
    float4 v4; v4.x=mn[j]; v4.y=mn[j+1]; v4.z=mn[j+2]; v4.w=mn[j+3];
    *(float4*)&M_new[((size_t)b*DD + k)*DD + d0 + j] = v4;
  }
  rowp[kl][dg] = ss;
  for (int o=1;o<64;o<<=1) nsq += __shfl_xor(nsq, o);
  if ((tid&63)==0) redb[tid>>6] = nsq;
  __syncthreads();
  if (tid == 0) atomicAdd(&scal[2], redb[0]+redb[1]+redb[2]+redb[3]);
  if (tid < 32) {
    float t2 = 0.f;
#pragma unroll
    for (int g=0; g<8; ++g) t2 += rowp[tid][g];
    float nrm = sqrtf(t2);
    rns_arr[(size_t)b*DD + kq*32 + tid] = 1.f / fmaxf(nrm, 1e-12f);
  }
}

// ---------------------------------------------------------------------------
// K2d: diversity loss partials.
// ---------------------------------------------------------------------------
__global__ void k2d(const float* __restrict__ M_new, const float* __restrict__ rns_arr,
                    float* __restrict__ scal)
{
  __shared__ float kr[4][128];
  __shared__ float redb[4];
  int tid = threadIdx.x;
  int b = blockIdx.x >> 5, kq = blockIdx.x & 31;
  for (int i = tid; i < 4*128; i += 256) {
    int ki = i >> 7, d = i & 127;
    kr[ki][d] = M_new[((size_t)b*DD + kq*4 + ki)*DD + d];
  }
  __syncthreads();
  int j = tid & 127, kh = tid >> 7;
  const float* mj = &M_new[((size_t)b*DD + j)*DD];
  float rj = rns_arr[(size_t)b*DD + j];
  float dv = 0.f;
#pragma unroll
  for (int ki2 = 0; ki2 < 2; ++ki2) {
    int kil = kh*2 + ki2;
    int kk = kq*4 + kil;
    float dot = 0.f;
    for (int d = 0; d < 128; d += 4) {
      float4 a = *(const float4*)(mj + d);
      dot += a.x*kr[kil][d] + a.y*kr[kil][d+1] + a.z*kr[kil][d+2] + a.w*kr[kil][d+3];
    }
    if (kk != j) {
      float sv = dot * rj * rns_arr[(size_t)b*DD + kk];
      dv += sv*sv;
    }
  }
  for (int o=1;o<64;o<<=1) dv += __shfl_xor(dv, o);
  if ((tid&63)==0) redb[tid>>6] = dv;
  __syncthreads();
  if (tid==0) atomicAdd(&scal[3], redb[0]+redb[1]+redb[2]+redb[3]);
}

// ---------------------------------------------------------------------------
// K3: read attention via MFMA fp16 (fp32 softmax/accum).
// ---------------------------------------------------------------------------
__launch_bounds__(256, 1)
__global__ void k3(const float* __restrict__ Q_r, const float* __restrict__ M_new,
                   const float* __restrict__ scal, float* __restrict__ out)
{
  __shared__ __align__(16) _Float16 Mq[128*132];  // [key][d]   (QK B-frags)
  __shared__ __align__(16) _Float16 Mt[128*136];  // [d][key]   (PV B-frags)
  __shared__ __align__(16) _Float16 Ps[64*132];   // [token][key] (PV A-frags)
  int tid = threadIdx.x;
  int b = blockIdx.x >> 6, tile = blockIdx.x & 63;
  int t0 = tile*64;
  if (blockIdx.x == 0 && tid == 0) {
    float loss = 0.01f*(scal[2]*(1.f/SSEG)) + 0.1f*(scal[3]*(1.f/(BB*DD*DD)));
    out[(size_t)MT*DD] = loss;
  }
  const float4* m4 = (const float4*)(M_new + (size_t)b*DD*DD);
#pragma unroll
  for (int it = 0; it < 4; ++it) {
    int sb = it*256 + tid;
    int rb = sb & 31, cb = sb >> 5;
    int r0 = rb*4, c0 = cb*4;
    float a[4][4];
#pragma unroll
    for (int j = 0; j < 4; ++j) {
      float4 v = m4[(size_t)(r0+j)*32 + cb];
      a[j][0]=v.x; a[j][1]=v.y; a[j][2]=v.z; a[j][3]=v.w;
    }
#pragma unroll
    for (int j = 0; j < 4; ++j) {
      half4v h; h.x=(_Float16)a[j][0]; h.y=(_Float16)a[j][1];
                h.z=(_Float16)a[j][2]; h.w=(_Float16)a[j][3];
      *(half4v*)&Mq[(r0+j)*132 + c0] = h;
    }
#pragma unroll
    for (int j2 = 0; j2 < 4; ++j2) {
      half4v h; h.x=(_Float16)a[0][j2]; h.y=(_Float16)a[1][j2];
                h.z=(_Float16)a[2][j2]; h.w=(_Float16)a[3][j2];
      *(half4v*)&Mt[(c0+j2)*136 + r0] = h;
    }
  }
  int w = tid >> 6, lane = tid & 63;
  int fcol = lane & 15, kq = lane >> 4;
  int tokA = t0 + w*16 + fcol;
  size_t qbase = ((size_t)b*TT + tokA)*DD;
  half8 af[4];
#pragma unroll
  for (int ks = 0; ks < 4; ++ks) {
    float4 q0 = *(const float4*)&Q_r[qbase + ks*32 + kq*8];
    float4 q1 = *(const float4*)&Q_r[qbase + ks*32 + kq*8 + 4];
    half8 h;
    h[0]=(_Float16)q0.x; h[1]=(_Float16)q0.y; h[2]=(_Float16)q0.z; h[3]=(_Float16)q0.w;
    h[4]=(_Float16)q1.x; h[5]=(_Float16)q1.y; h[6]=(_Float16)q1.z; h[7]=(_Float16)q1.w;
    af[ks] = h;
  }
  __syncthreads();
  f32x4 sacc[8];
#pragma unroll
  for (int nt = 0; nt < 8; ++nt) sacc[nt] = (f32x4){0.f,0.f,0.f,0.f};
#pragma unroll
  for (int nt = 0; nt < 8; ++nt)
#pragma unroll
    for (int ks = 0; ks < 4; ++ks) {
      half8 bf = *(half8*)&Mq[(nt*16 + fcol)*132 + ks*32 + kq*8];
      sacc[nt] = __builtin_amdgcn_mfma_f32_16x16x32_f16(af[ks], bf, sacc[nt], 0,0,0);
    }
#pragma unroll
  for (int nt = 0; nt < 8; ++nt)
#pragma unroll
    for (int r = 0; r < 4; ++r) sacc[nt][r] *= 2.f;
  float mx[4], sm[4];
#pragma unroll
  for (int r = 0; r < 4; ++r) {
    float m = sacc[0][r];
#pragma unroll
    for (int nt = 1; nt < 8; ++nt) m = fmaxf(m, sacc[nt][r]);
#pragma unroll
    for (int o = 1; o < 16; o <<= 1) m = fmaxf(m, __shfl_xor(m, o));
    mx[r] = m;
  }
#pragma unroll
  for (int r = 0; r < 4; ++r) sm[r] = 0.f;
#pragma unroll
  for (int nt = 0; nt < 8; ++nt)
#pragma unroll
    for (int r = 0; r < 4; ++r) {
      float e = __expf(sacc[nt][r] - mx[r]);
      sacc[nt][r] = e; sm[r] += e;
    }
#pragma unroll
  for (int r = 0; r < 4; ++r) {
    float s = sm[r];
#pragma unroll
    for (int o = 1; o < 16; o <<= 1) s += __shfl_xor(s, o);
    sm[r] = 1.f / s;
  }
#pragma unroll
  for (int nt = 0; nt < 8; ++nt)
#pragma unroll
    for (int r = 0; r < 4; ++r) {
      int tk = w*16 + kq*4 + r;
      Ps[tk*132 + nt*16 + fcol] = (_Float16)(sacc[nt][r]*sm[r]);
    }
  __syncthreads();
  half8 pf[4];
#pragma unroll
  for (int ks = 0; ks < 4; ++ks)
    pf[ks] = *(half8*)&Ps[(w*16 + fcol)*132 + ks*32 + kq*8];
  f32x4 cacc[8];
#pragma unroll
  for (int nt = 0; nt < 8; ++nt) cacc[nt] = (f32x4){0.f,0.f,0.f,0.f};
#pragma unroll
  for (int nt = 0; nt < 8; ++nt)
#pragma unroll
    for (int ks = 0; ks < 4; ++ks) {
      half8 bf = *(half8*)&Mt[(nt*16 + fcol)*136 + ks*32 + kq*8];
      cacc[nt] = __builtin_amdgcn_mfma_f32_16x16x32_f16(pf[ks], bf, cacc[nt], 0,0,0);
    }
#pragma unroll
  for (int nt = 0; nt < 8; ++nt)
#pragma unroll
    for (int r = 0; r < 4; ++r) {
      int tk = t0 + w*16 + kq*4 + r;
      out[((size_t)b*TT + tk)*DD + nt*16 + fcol] = cacc[nt][r];
    }
}

// ---------------------------------------------------------------------------
extern "C" void kernel_launch(void* const* d_in, const int* in_sizes, int n_in,
                              void* d_out, int out_size, void* d_ws, size_t ws_size,
                              hipStream_t stream)
{
  (void)in_sizes; (void)n_in; (void)out_size; (void)ws_size;
  const float* H       = (const float*)d_in[0];
  const float* Mmat    = (const float*)d_in[1];
  const float* ln_g    = (const float*)d_in[2];
  const float* ln_b    = (const float*)d_in[3];
  const float* W_eta_w = (const float*)d_in[4];
  const float* W_eta_b = (const float*)d_in[5];
  const float* sum_q   = (const float*)d_in[6];
  const float* sp_w    = (const float*)d_in[7];
  const float* sp_b    = (const float*)d_in[8];
  const float* eta_ch  = (const float*)d_in[9];
  const float* temp    = (const float*)d_in[10];
  const float* W_qkv   = (const float*)d_in[11];
  float* out           = (float*)d_out;

  char* wsb = (char*)d_ws;
  size_t off = 0;
  auto alloc = [&](size_t bytes) -> void* {
    void* p = wsb + off;
    off = (off + bytes + 255) & ~(size_t)255;
    return p;
  };
  _Float16* Bp   = (_Float16*)alloc((size_t)NCOL*HD*2);
  float* s_vec   = (float*)alloc(NCOL*4);
  float* cb_vec  = (float*)alloc(NCOL*4);
  float* we2     = (float*)alloc(HD*4);
  float* scal    = (float*)alloc(4*4);
  float* Q_r     = (float*)alloc((size_t)MT*DD*4);
  float* Zeta    = (float*)alloc((size_t)BB*SSEG*DD*4);
  float* A_seg   = (float*)alloc((size_t)BB*SSEG*DD*4);
  float* eta_seg = (float*)alloc((size_t)BB*SSEG*4);
  float* M_new   = (float*)alloc((size_t)BB*DD*DD*4);
  float* rns_arr = (float*)alloc((size_t)BB*DD*4);

  hipLaunchKernelGGL(k_pre, dim3(NCOL+1), dim3(256), 0, stream,
                     ln_g, ln_b, sp_w, sp_b, W_qkv, W_eta_w, W_eta_b,
                     Bp, s_vec, cb_vec, we2, scal);
  hipLaunchKernelGGL(k01, dim3((MT/64)*2), dim3(256), 0, stream,
                     H, Bp, s_vec, cb_vec, we2, scal, sum_q, Mmat, temp,
                     Q_r, Zeta, A_seg, eta_seg);
  hipLaunchKernelGGL(k2b, dim3(16), dim3(256), 0, stream,
                     A_seg, Zeta, eta_seg, Mmat, eta_ch, M_new, rns_arr, scal);
  hipLaunchKernelGGL(k2d, dim3(128), dim3(256), 0, stream,
                     M_new, rns_arr, scal);
  hipLaunchKernelGGL(k3, dim3(256), dim3(256), 0, stream,
                     Q_r, M_new, scal, out);
}